// Round 14
// baseline (882.350 us; speedup 1.0000x reference)
//
#include <hip/hip_runtime.h>
#include <hip/hip_bf16.h>

typedef __bf16 bf16;
typedef __bf16 bf16x8 __attribute__((ext_vector_type(8)));
typedef __bf16 bf16x4 __attribute__((ext_vector_type(4)));
typedef float  f32x4  __attribute__((ext_vector_type(4)));

#define S_LEN   6400
#define NBATCH  2
#define DMODEL  2048
#define NHEADS  16
#define DHEAD   128
#define NSEG    50
#define SEGLEN  128
#define MROWS   (S_LEN*NBATCH)     // 12800
#define QKV_N   (3*DMODEL)         // 6144

static __device__ __forceinline__ f32x4 mfma16x16x32(bf16x8 a, bf16x8 b, f32x4 c) {
    return __builtin_amdgcn_mfma_f32_16x16x32_bf16(a, b, c, 0, 0, 0);
}
static __device__ __forceinline__ void gload_lds16(const bf16* g, bf16* l) {
    __builtin_amdgcn_global_load_lds(
        (const __attribute__((address_space(1))) void*)g,
        (__attribute__((address_space(3))) void*)l, 16, 0, 0);
}
static __device__ __forceinline__ float elu1(float x) {
    return x > 0.f ? x + 1.f : __expf(x);
}

// ---------------------------------------------------------------------------
// prep_inputs: one launch for {fp32->bf16 hidden, W_qkv^T, W_o^T}.
// ---------------------------------------------------------------------------
__global__ void prep_inputs(const float* __restrict__ hidden, bf16* __restrict__ abf,
                            const float* __restrict__ w_qkv, bf16* __restrict__ wqkvT,
                            const float* __restrict__ w_o,   bf16* __restrict__ woT)
{
    __shared__ float tile[32][33];
    const int bid = blockIdx.x;
    if (bid < 2048) {
        const int n8 = MROWS*DMODEL/8;
        const int stride = 2048 * 256;
        for (int i = bid * 256 + threadIdx.x; i < n8; i += stride) {
            const float4* p = (const float4*)(hidden + (size_t)i * 8);
            float4 v0 = p[0], v1 = p[1];
            bf16x8 o;
            o[0]=(bf16)v0.x; o[1]=(bf16)v0.y; o[2]=(bf16)v0.z; o[3]=(bf16)v0.w;
            o[4]=(bf16)v1.x; o[5]=(bf16)v1.y; o[6]=(bf16)v1.z; o[7]=(bf16)v1.w;
            *(bf16x8*)(abf + (size_t)i * 8) = o;
        }
        return;
    }
    const float* W; bf16* WT; int N, n0, k0;
    if (bid < 14336) {
        const int b2 = bid - 2048;
        W = w_qkv; WT = wqkvT; N = QKV_N;
        n0 = (b2 % 192) * 32; k0 = (b2 / 192) * 32;
    } else {
        const int b3 = bid - 14336;
        W = w_o; WT = woT; N = DMODEL;
        n0 = (b3 % 64) * 32; k0 = (b3 / 64) * 32;
    }
    const int tx = threadIdx.x & 31, ty = threadIdx.x >> 5;
    #pragma unroll
    for (int i = 0; i < 4; i++) {
        int kk = ty + i * 8;
        tile[kk][tx] = W[(size_t)(k0 + kk) * N + n0 + tx];
    }
    __syncthreads();
    #pragma unroll
    for (int i = 0; i < 4; i++) {
        int nn = ty + i * 8;
        WT[(size_t)(n0 + nn) * DMODEL + k0 + tx] = (bf16)tile[tx][nn];
    }
}

// ---------------------------------------------------------------------------
// gemm256 (r9 champion + XCD swizzle): 256x256 tile, BK=32, 512 thr, phase-
// split read-ahead, counted vmcnt(4), swizzled LDS (0 conflicts). 1001 TF.
// Grid is 1D (gM*gN, multiple of 8); bijective XCD-chunk swizzle so blocks
// sharing an A-panel (same x, adjacent y, 50 ids apart) stay on one XCD's L2.
// ---------------------------------------------------------------------------
template<bool CBF16>
__global__ __launch_bounds__(512, 2) void gemm256(const bf16* __restrict__ A,
                                                  const bf16* __restrict__ BT,
                                                  void* __restrict__ Cptr,
                                                  int Ndim, int gM)
{
    constexpr int K = DMODEL;
    constexpr int NT = K / 32;
    __shared__ __align__(16) bf16 a_sm[2][256*32];
    __shared__ __align__(16) bf16 b_sm[2][256*32];

    const int tid = threadIdx.x;
    const int l = tid & 63, wid = tid >> 6;
    const int wm = wid >> 2, wn = wid & 3;
    // XCD-chunk swizzle (nwg % 8 == 0 for both call sites)
    const int cpx = gridDim.x >> 3;
    const int swz = (blockIdx.x & 7) * cpx + (blockIdx.x >> 3);
    const int brow = (swz % gM) * 256, bcol = (swz / gM) * 256;
    const int l15 = l & 15, lg = l >> 4;

    const int st_mr  = tid >> 3;
    const int st_s0  = (tid & 7) ^ (st_mr & 7);
    const int st_row = 2 * st_mr + (st_s0 >> 2);
    const int st_col = (st_s0 & 3) << 3;
    const bf16* Asrc = A  + (size_t)(brow + st_row) * K + st_col;
    const bf16* Bsrc = BT + (size_t)(bcol + st_row) * K + st_col;

    int aoff[8], boff[4];
    #pragma unroll
    for (int mi = 0; mi < 8; mi++) {
        const int r = wm*128 + mi*16 + l15, mr = r >> 1;
        aoff[mi] = mr*64 + ((((( r & 1) << 2) | lg) ^ (mr & 7)) << 3);
    }
    #pragma unroll
    for (int ni = 0; ni < 4; ni++) {
        const int r = wn*64 + ni*16 + l15, mr = r >> 1;
        boff[ni] = mr*64 + ((((( r & 1) << 2) | lg) ^ (mr & 7)) << 3);
    }

    f32x4 acc[8][4];
    #pragma unroll
    for (int mi = 0; mi < 8; mi++)
        #pragma unroll
        for (int ni = 0; ni < 4; ni++)
            #pragma unroll
            for (int e = 0; e < 4; e++) acc[mi][ni][e] = 0.f;

    auto STAGE = [&](int buf, int kt2) {
        const int k0 = kt2 * 32;
        #pragma unroll
        for (int i = 0; i < 2; i++) {
            gload_lds16(Asrc + (size_t)(i*128) * K + k0, &a_sm[buf][i*4096 + tid*8]);
            gload_lds16(Bsrc + (size_t)(i*128) * K + k0, &b_sm[buf][i*4096 + tid*8]);
        }
    };

    bf16x8 af[4], ag[4], bfr[4];
    auto READ0 = [&](int buf) {
        #pragma unroll
        for (int mi = 0; mi < 4; mi++) af[mi]  = *(const bf16x8*)&a_sm[buf][aoff[mi]];
        #pragma unroll
        for (int ni = 0; ni < 4; ni++) bfr[ni] = *(const bf16x8*)&b_sm[buf][boff[ni]];
    };
    auto READ1 = [&](int buf) {
        #pragma unroll
        for (int mi = 0; mi < 4; mi++) ag[mi] = *(const bf16x8*)&a_sm[buf][aoff[4 + mi]];
    };
    auto MFMA_LO = [&]() {
        __builtin_amdgcn_s_setprio(1);
        #pragma unroll
        for (int mi = 0; mi < 4; mi++)
            #pragma unroll
            for (int ni = 0; ni < 4; ni++)
                acc[mi][ni] = mfma16x16x32(af[mi], bfr[ni], acc[mi][ni]);
        __builtin_amdgcn_s_setprio(0);
    };
    auto MFMA_HI = [&]() {
        __builtin_amdgcn_s_setprio(1);
        #pragma unroll
        for (int mi = 0; mi < 4; mi++)
            #pragma unroll
            for (int ni = 0; ni < 4; ni++)
                acc[4 + mi][ni] = mfma16x16x32(ag[mi], bfr[ni], acc[4 + mi][ni]);
        __builtin_amdgcn_s_setprio(0);
    };

    STAGE(0, 0);
    STAGE(1, 1);
    asm volatile("s_waitcnt vmcnt(4)" ::: "memory");
    __builtin_amdgcn_sched_barrier(0);
    __builtin_amdgcn_s_barrier();
    READ0(0);

    for (int tp = 0; tp < NT - 2; tp += 2) {
        READ1(0);
        __builtin_amdgcn_sched_barrier(0);
        MFMA_LO();
        asm volatile("s_waitcnt lgkmcnt(0)" ::: "memory");
        __builtin_amdgcn_sched_barrier(0);
        __builtin_amdgcn_s_barrier();
        STAGE(0, tp + 2);
        __builtin_amdgcn_sched_barrier(0);
        MFMA_HI();
        asm volatile("s_waitcnt vmcnt(4)" ::: "memory");
        __builtin_amdgcn_sched_barrier(0);
        __builtin_amdgcn_s_barrier();

        READ0(1);
        READ1(1);
        __builtin_amdgcn_sched_barrier(0);
        MFMA_LO();
        asm volatile("s_waitcnt lgkmcnt(0)" ::: "memory");
        __builtin_amdgcn_sched_barrier(0);
        __builtin_amdgcn_s_barrier();
        STAGE(1, tp + 3);
        __builtin_amdgcn_sched_barrier(0);
        MFMA_HI();
        asm volatile("s_waitcnt vmcnt(4)" ::: "memory");
        __builtin_amdgcn_sched_barrier(0);
        __builtin_amdgcn_s_barrier();
        READ0(0);
    }

    READ1(0);
    __builtin_amdgcn_sched_barrier(0);
    MFMA_LO();
    asm volatile("s_waitcnt lgkmcnt(0)" ::: "memory");
    __builtin_amdgcn_sched_barrier(0);
    MFMA_HI();
    asm volatile("s_waitcnt vmcnt(0)" ::: "memory");
    __builtin_amdgcn_sched_barrier(0);
    __builtin_amdgcn_s_barrier();
    READ0(1);
    READ1(1);
    __builtin_amdgcn_sched_barrier(0);
    MFMA_LO();
    asm volatile("s_waitcnt lgkmcnt(0)" ::: "memory");
    __builtin_amdgcn_sched_barrier(0);
    MFMA_HI();

    #pragma unroll
    for (int mi = 0; mi < 8; mi++)
        #pragma unroll
        for (int ni = 0; ni < 4; ni++) {
            const int row = brow + wm*128 + mi*16 + lg*4;
            const int col = bcol + wn*64 + ni*16 + l15;
            #pragma unroll
            for (int j = 0; j < 4; j++) {
                float v = acc[mi][ni][j];
                if (CBF16) ((bf16*)Cptr)[(size_t)(row + j) * Ndim + col] = (bf16)v;
                else       ((float*)Cptr)[(size_t)(row + j) * Ndim + col] = v;
            }
        }
}

// ---------------------------------------------------------------------------
// attn_local (fused): lob = (1-g)*local_out; ksum[bh,n,dk] = sum_s elu1(k);
// Ub[seg] = skT @ v.
// ---------------------------------------------------------------------------
__global__ void attn_local(const bf16* __restrict__ qkv,
                           bf16* __restrict__ lob,
                           const float* __restrict__ bal,
                           float* __restrict__ ksum,
                           bf16* __restrict__ Ub)
{
    __shared__ bf16 qp_sm [128*136];
    __shared__ bf16 k_sm  [128*136];
    __shared__ bf16 vT_sm [128*136];
    __shared__ bf16 skT_sm[128*136];
    const int bid = blockIdx.x;
    const int h = bid & 15, b = (bid >> 4) & 1, n = bid >> 5;
    const int bh = b*NHEADS + h;
    const int tid = threadIdx.x, l = tid & 63, w = tid >> 6;
    const int l15 = l & 15, lk = (l >> 4) * 8, r0 = (l >> 4) * 4;
    const float g  = 1.f / (1.f + __expf(-bal[h]));
    const float w1 = 1.f - g;

    {
        const int srow = tid >> 1, off = (tid & 1) << 6;
        const size_t gb = ((size_t)(n*SEGLEN + srow)*NBATCH + b)*QKV_N + h*DHEAD + off;
        const bf16* qsrc = qkv + gb;
        const bf16* ksrc = qkv + gb + DMODEL;
        const bf16* vsrc = qkv + gb + 2*DMODEL;
        #pragma unroll
        for (int j = 0; j < 64; j += 8) {
            bf16x8 kv = *(const bf16x8*)(ksrc + j);
            bf16x8 vv = *(const bf16x8*)(vsrc + j);
            *(bf16x8*)&qp_sm[srow*136 + off + j] = *(const bf16x8*)(qsrc + j);
            *(bf16x8*)&k_sm [srow*136 + off + j] = kv;
            #pragma unroll
            for (int e = 0; e < 8; e++) {
                vT_sm [(off + j + e)*136 + srow] = vv[e];
                skT_sm[(off + j + e)*136 + srow] = (bf16)elu1((float)kv[e]);
            }
        }
    }
    __syncthreads();

    f32x4 sc[2][8];
    for (int mi = 0; mi < 2; mi++) for (int ni = 0; ni < 8; ni++)
        for (int e = 0; e < 4; e++) sc[mi][ni][e] = 0.f;
    #pragma unroll
    for (int ks = 0; ks < 4; ks++) {
        const int ko = ks*32 + lk;
        bf16x8 aq[2], bk[8];
        #pragma unroll
        for (int mi = 0; mi < 2; mi++)
            aq[mi] = *(const bf16x8*)&qp_sm[(w*32 + mi*16 + l15)*136 + ko];
        #pragma unroll
        for (int ni = 0; ni < 8; ni++)
            bk[ni] = *(const bf16x8*)&k_sm[(ni*16 + l15)*136 + ko];
        #pragma unroll
        for (int mi = 0; mi < 2; mi++)
            #pragma unroll
            for (int ni = 0; ni < 8; ni++)
                sc[mi][ni] = mfma16x16x32(aq[mi], bk[ni], sc[mi][ni]);
    }
    __syncthreads();

    const float scale = 0.088388347648318433f;
    #pragma unroll
    for (int mi = 0; mi < 2; mi++) {
        #pragma unroll
        for (int j = 0; j < 4; j++) {
            const int R = w*32 + mi*16 + r0 + j;
            float v[8]; float mx = -1e30f;
            #pragma unroll
            for (int ni = 0; ni < 8; ni++) {
                float x = sc[mi][ni][j] * scale;
                if (ni*16 + l15 > R) x = -1e9f;
                v[ni] = x; mx = fmaxf(mx, x);
            }
            #pragma unroll
            for (int d = 1; d < 16; d <<= 1) mx = fmaxf(mx, __shfl_xor(mx, d));
            float sum = 0.f;
            #pragma unroll
            for (int ni = 0; ni < 8; ni++) { v[ni] = __expf(v[ni] - mx); sum += v[ni]; }
            #pragma unroll
            for (int d = 1; d < 16; d <<= 1) sum += __shfl_xor(sum, d);
            const float inv = 1.f / sum;
            #pragma unroll
            for (int ni = 0; ni < 8; ni++)
                qp_sm[R*136 + ni*16 + l15] = (bf16)(v[ni] * inv);
        }
    }
    __syncthreads();

    f32x4 o[2][8];
    for (int mi = 0; mi < 2; mi++) for (int ni = 0; ni < 8; ni++)
        for (int e = 0; e < 4; e++) o[mi][ni][e] = 0.f;
    #pragma unroll
    for (int ks = 0; ks < 4; ks++) {
        const int ko = ks*32 + lk;
        bf16x8 ap[2], bv[8];
        #pragma unroll
        for (int mi = 0; mi < 2; mi++)
            ap[mi] = *(const bf16x8*)&qp_sm[(w*32 + mi*16 + l15)*136 + ko];
        #pragma unroll
        for (int ni = 0; ni < 8; ni++)
            bv[ni] = *(const bf16x8*)&vT_sm[(ni*16 + l15)*136 + ko];
        #pragma unroll
        for (int mi = 0; mi < 2; mi++)
            #pragma unroll
            for (int ni = 0; ni < 8; ni++)
                o[mi][ni] = mfma16x16x32(ap[mi], bv[ni], o[mi][ni]);
    }

    #pragma unroll
    for (int mi = 0; mi < 2; mi++)
        #pragma unroll
        for (int ni = 0; ni < 8; ni++) {
            const int R = w*32 + mi*16 + r0;
            const int c = ni*16 + l15;
            #pragma unroll
            for (int j = 0; j < 4; j++)
                lob[((size_t)(n*SEGLEN + R + j)*NBATCH + b)*DMODEL + h*DHEAD + c] =
                    (bf16)(w1 * o[mi][ni][j]);
        }

    if (tid < 128) {
        float a = 0.f;
        const bf16* row = &skT_sm[tid*136];
        #pragma unroll
        for (int ss = 0; ss < 128; ss += 8) {
            bf16x8 v8 = *(const bf16x8*)(row + ss);
            #pragma unroll
            for (int e = 0; e < 8; e++) a += (float)v8[e];
        }
        ksum[((size_t)bh*NSEG + n)*128 + tid] = a;
    }

    {
        const int wr = w >> 1, wc = w & 1;
        const size_t seg = (size_t)bh*NSEG + n;
        f32x4 ua[4][4];
        for (int mi = 0; mi < 4; mi++) for (int ni = 0; ni < 4; ni++)
            for (int e = 0; e < 4; e++) ua[mi][ni][e] = 0.f;
        #pragma unroll
        for (int ks = 0; ks < 4; ks++) {
            const int ko = ks*32 + lk;
            bf16x8 auf[4], bv[4];
            #pragma unroll
            for (int mi = 0; mi < 4; mi++)
                auf[mi] = *(const bf16x8*)&skT_sm[(wr*64 + mi*16 + l15)*136 + ko];
            #pragma unroll
            for (int ni = 0; ni < 4; ni++)
                bv[ni] = *(const bf16x8*)&vT_sm[(wc*64 + ni*16 + l15)*136 + ko];
            #pragma unroll
            for (int mi = 0; mi < 4; mi++)
                #pragma unroll
                for (int ni = 0; ni < 4; ni++)
                    ua[mi][ni] = mfma16x16x32(auf[mi], bv[ni], ua[mi][ni]);
        }
        #pragma unroll
        for (int mi = 0; mi < 4; mi++)
            #pragma unroll
            for (int ni = 0; ni < 4; ni++) {
                const int row = wr*64 + mi*16 + r0, col = wc*64 + ni*16 + l15;
                #pragma unroll
                for (int j = 0; j < 4; j++)
                    Ub[(seg << 14) + (size_t)(row + j)*128 + col] = (bf16)ua[mi][ni][j];
            }
    }
}

// ---------------------------------------------------------------------------
// scan2: mem_n = mem_{n-1} - skT@((sk@mem_{n-1})/denk) + U_n ;
//        retr  = (sq@mem_{n-1})/denq ; lob += g*retr.
// Norm prefix in registers. Grid 256, XCD-locality decode bh=bid&31.
// ---------------------------------------------------------------------------
__global__ __launch_bounds__(256, 1) void scan2(const bf16* __restrict__ qkv,
                                                const bf16* __restrict__ Ub,
                                                const float* __restrict__ ksum,
                                                bf16* __restrict__ lob,
                                                const float* __restrict__ bal)
{
    __shared__ bf16 memT[16*136];
    __shared__ bf16 skT [128*136];
    __shared__ bf16 yT  [16*136];
    const int bid = blockIdx.x;
    const int bh = bid & 31, dq = bid >> 5;
    const int b = bh >> 4, h = bh & 15;
    const int tid = threadIdx.x, l = tid & 63, w = tid >> 6;
    const int l15 = l & 15, lk = (l >> 4) * 8, r0 = (l >> 4) * 4;
    const float g = 1.f / (1.f + __expf(-bal[h]));
    const size_t segb = (size_t)bh * NSEG;
    const int cdv = dq*16 + l15;

    float mast[2][4];
    #pragma unroll
    for (int mi = 0; mi < 2; mi++)
        #pragma unroll
        for (int j = 0; j < 4; j++) {
            const int row = w*32 + mi*16 + r0 + j;
            mast[mi][j] = (float)Ub[(segb << 14) + (size_t)row*128 + cdv];
            memT[l15*136 + row] = (bf16)mast[mi][j];
        }
    __syncthreads();

    float nrm[4][8];
    {
        const float* np = ksum + segb*128;
        #pragma unroll
        for (int ks = 0; ks < 4; ks++) {
            float4 a0 = *(const float4*)(np + ks*32 + lk);
            float4 a1 = *(const float4*)(np + ks*32 + lk + 4);
            nrm[ks][0]=a0.x; nrm[ks][1]=a0.y; nrm[ks][2]=a0.z; nrm[ks][3]=a0.w;
            nrm[ks][4]=a1.x; nrm[ks][5]=a1.y; nrm[ks][6]=a1.z; nrm[ks][7]=a1.w;
        }
    }

    bf16x8 qA[8], kA[8], qB[8], kB[8];

    auto loadraw = [&](int n2, bf16x8* qr, bf16x8* kr) {
        #pragma unroll
        for (int mi = 0; mi < 2; mi++)
            #pragma unroll
            for (int ks = 0; ks < 4; ks++) {
                const size_t base =
                    ((size_t)(n2*SEGLEN + w*32 + mi*16 + l15)*NBATCH + b)*QKV_N
                    + h*DHEAD + ks*32 + lk;
                qr[mi*4 + ks] = *(const bf16x8*)(qkv + base);
                kr[mi*4 + ks] = *(const bf16x8*)(qkv + base + DMODEL);
            }
    };

    auto step = [&](int n, bf16x8* curq, bf16x8* curk, bf16x8* nxtq, bf16x8* nxtk) {
        float uval[2][4], lv[2][4];
        #pragma unroll
        for (int mi = 0; mi < 2; mi++)
            #pragma unroll
            for (int j = 0; j < 4; j++) {
                const int sx = w*32 + mi*16 + r0 + j;
                uval[mi][j] = (float)Ub[((segb + n) << 14) + (size_t)sx*128 + cdv];
                lv[mi][j] = (float)lob[((size_t)(n*SEGLEN + sx)*NBATCH + b)*DMODEL
                                       + h*DHEAD + cdv];
            }
        bf16x8 sqf[8], skf[8];
        #pragma unroll
        for (int f = 0; f < 8; f++) {
            bf16x8 qv = curq[f], kv = curk[f], sq_, sk_;
            #pragma unroll
            for (int e = 0; e < 8; e++) {
                sq_[e] = (bf16)elu1((float)qv[e]);
                sk_[e] = (bf16)elu1((float)kv[e]);
            }
            sqf[f] = sq_; skf[f] = sk_;
        }
        float dqv[2][4], ivk[2][4];
        #pragma unroll
        for (int mi = 0; mi < 2; mi++) {
            float aq = 0.f, ak = 0.f;
            #pragma unroll
            for (int ks = 0; ks < 4; ks++)
                #pragma unroll
                for (int e = 0; e < 8; e++) {
                    aq += (float)sqf[mi*4 + ks][e] * nrm[ks][e];
                    ak += (float)skf[mi*4 + ks][e] * nrm[ks][e];
                }
            aq += __shfl_xor(aq, 16); aq += __shfl_xor(aq, 32);
            ak += __shfl_xor(ak, 16); ak += __shfl_xor(ak, 32);
            #pragma unroll
            for (int j = 0; j < 4; j++) {
                dqv[mi][j] = __shfl(aq, r0 + j);
                ivk[mi][j] = 1.f / __shfl(ak, r0 + j);
            }
        }
        {
            const float* np = ksum + (segb + n)*128;
            #pragma unroll
            for (int ks = 0; ks < 4; ks++) {
                float4 a0 = *(const float4*)(np + ks*32 + lk);
                float4 a1 = *(const float4*)(np + ks*32 + lk + 4);
                nrm[ks][0]+=a0.x; nrm[ks][1]+=a0.y; nrm[ks][2]+=a0.z; nrm[ks][3]+=a0.w;
                nrm[ks][4]+=a1.x; nrm[ks][5]+=a1.y; nrm[ks][6]+=a1.z; nrm[ks][7]+=a1.w;
            }
        }
        #pragma unroll
        for (int mi = 0; mi < 2; mi++)
            #pragma unroll
            for (int ks = 0; ks < 4; ks++)
                #pragma unroll
                for (int e = 0; e < 8; e++)
                    skT[(ks*32 + lk + e)*136 + w*32 + mi*16 + l15] = skf[mi*4 + ks][e];
        f32x4 racc[2], yacc[2];
        #pragma unroll
        for (int mi = 0; mi < 2; mi++)
            #pragma unroll
            for (int e = 0; e < 4; e++) { racc[mi][e] = 0.f; yacc[mi][e] = 0.f; }
        #pragma unroll
        for (int ks = 0; ks < 4; ks++) {
            bf16x8 bm = *(const bf16x8*)&memT[l15*136 + ks*32 + lk];
            #pragma unroll
            for (int mi = 0; mi < 2; mi++) {
                racc[mi] = mfma16x16x32(sqf[mi*4 + ks], bm, racc[mi]);
                yacc[mi] = mfma16x16x32(skf[mi*4 + ks], bm, yacc[mi]);
            }
        }
        if (n < NSEG - 1) loadraw(n + 1, nxtq, nxtk);
        #pragma unroll
        for (int mi = 0; mi < 2; mi++)
            #pragma unroll
            for (int j = 0; j < 4; j++)
                yT[l15*136 + w*32 + mi*16 + r0 + j] = (bf16)(yacc[mi][j] * ivk[mi][j]);
        __syncthreads();
        f32x4 zacc[2];
        #pragma unroll
        for (int mi = 0; mi < 2; mi++)
            #pragma unroll
            for (int e = 0; e < 4; e++) zacc[mi][e] = 0.f;
        #pragma unroll
        for (int ks = 0; ks < 4; ks++) {
            bf16x8 bz = *(const bf16x8*)&yT[l15*136 + ks*32 + lk];
            #pragma unroll
            for (int mi = 0; mi < 2; mi++) {
                bf16x8 az = *(const bf16x8*)&skT[(w*32 + mi*16 + l15)*136 + ks*32 + lk];
                zacc[mi] = mfma16x16x32(az, bz, zacc[mi]);
            }
        }
        #pragma unroll
        for (int mi = 0; mi < 2; mi++)
            #pragma unroll
            for (int j = 0; j < 4; j++) {
                const int sx = w*32 + mi*16 + r0 + j;
                const float rv = racc[mi][j] / dqv[mi][j];
                lob[((size_t)(n*SEGLEN + sx)*NBATCH + b)*DMODEL + h*DHEAD + cdv] =
                    (bf16)(lv[mi][j] + g * rv);
                mast[mi][j] += uval[mi][j] - zacc[mi][j];
                memT[l15*136 + sx] = (bf16)mast[mi][j];
            }
        __syncthreads();
    };

    loadraw(1, qA, kA);
    for (int n = 1; n < NSEG; n += 2) {
        step(n, qA, kA, qB, kB);
        if (n + 1 < NSEG) step(n + 1, qB, kB, qA, kA);
    }
}

// ---------------------------------------------------------------------------
// Workspace layout (max 295,698,432 B, proven-safe):
//   [0)            qkvb  157,286,400
//   [157,286,400)  lob    52,428,800
//   [209,715,200)  woT     8,388,608
//   [218,103,808)  abf    52,428,800   -> reused as Ub (bf16) after QKV GEMM
//   [270,532,608)  wqkvT  25,165,824   -> reused as ksum
// ---------------------------------------------------------------------------
extern "C" void kernel_launch(void* const* d_in, const int* in_sizes, int n_in,
                              void* d_out, int out_size, void* d_ws, size_t ws_size,
                              hipStream_t stream)
{
    (void)in_sizes; (void)n_in; (void)out_size; (void)ws_size;
    const float* hidden = (const float*)d_in[0];
    const float* w_qkv  = (const float*)d_in[2];
    const float* w_o    = (const float*)d_in[3];
    const float* bal    = (const float*)d_in[4];

    char* ws = (char*)d_ws;
    bf16*  qkvb  = (bf16*)ws;
    bf16*  lob   = (bf16*)(ws + 157286400);
    bf16*  woT   = (bf16*)(ws + 209715200);
    bf16*  abf   = (bf16*)(ws + 218103808);
    bf16*  Ub    = abf;
    bf16*  wqkvT = (bf16*)(ws + 270532608);
    float* ksum  = (float*)(ws + 270532608);

    dim3 blk(256);
    prep_inputs<<<18432, blk, 0, stream>>>(hidden, abf, w_qkv, wqkvT, w_o, woT);

    gemm256<true><<<(MROWS/256)*(QKV_N/256), 512, 0, stream>>>(
        abf, wqkvT, qkvb, QKV_N, MROWS/256);

    attn_local<<<dim3(NSEG*NBATCH*NHEADS), blk, 0, stream>>>(qkvb, lob, bal, ksum, Ub);
    scan2<<<256, blk, 0, stream>>>(qkvb, Ub, ksum, lob, bal);

    gemm256<false><<<(MROWS/256)*(DMODEL/256), 512, 0, stream>>>(
        lob, woT, d_out, DMODEL, MROWS/256);
}

// Round 15
// 871.170 us; speedup vs baseline: 1.0128x; 1.0128x over previous
//
#include <hip/hip_runtime.h>
#include <hip/hip_bf16.h>

typedef __bf16 bf16;
typedef __bf16 bf16x8 __attribute__((ext_vector_type(8)));
typedef __bf16 bf16x4 __attribute__((ext_vector_type(4)));
typedef float  f32x4  __attribute__((ext_vector_type(4)));

#define S_LEN   6400
#define NBATCH  2
#define DMODEL  2048
#define NHEADS  16
#define DHEAD   128
#define NSEG    50
#define SEGLEN  128
#define MROWS   (S_LEN*NBATCH)     // 12800
#define QKV_N   (3*DMODEL)         // 6144

static __device__ __forceinline__ f32x4 mfma16x16x32(bf16x8 a, bf16x8 b, f32x4 c) {
    return __builtin_amdgcn_mfma_f32_16x16x32_bf16(a, b, c, 0, 0, 0);
}
static __device__ __forceinline__ void gload_lds16(const bf16* g, bf16* l) {
    __builtin_amdgcn_global_load_lds(
        (const __attribute__((address_space(1))) void*)g,
        (__attribute__((address_space(3))) void*)l, 16, 0, 0);
}
static __device__ __forceinline__ float elu1(float x) {
    return x > 0.f ? x + 1.f : __expf(x);
}

// ---------------------------------------------------------------------------
// prep_inputs: one launch for {fp32->bf16 hidden, W_qkv^T, W_o^T}.
// ---------------------------------------------------------------------------
__global__ void prep_inputs(const float* __restrict__ hidden, bf16* __restrict__ abf,
                            const float* __restrict__ w_qkv, bf16* __restrict__ wqkvT,
                            const float* __restrict__ w_o,   bf16* __restrict__ woT)
{
    __shared__ float tile[32][33];
    const int bid = blockIdx.x;
    if (bid < 2048) {
        const int n8 = MROWS*DMODEL/8;
        const int stride = 2048 * 256;
        for (int i = bid * 256 + threadIdx.x; i < n8; i += stride) {
            const float4* p = (const float4*)(hidden + (size_t)i * 8);
            float4 v0 = p[0], v1 = p[1];
            bf16x8 o;
            o[0]=(bf16)v0.x; o[1]=(bf16)v0.y; o[2]=(bf16)v0.z; o[3]=(bf16)v0.w;
            o[4]=(bf16)v1.x; o[5]=(bf16)v1.y; o[6]=(bf16)v1.z; o[7]=(bf16)v1.w;
            *(bf16x8*)(abf + (size_t)i * 8) = o;
        }
        return;
    }
    const float* W; bf16* WT; int N, n0, k0;
    if (bid < 14336) {
        const int b2 = bid - 2048;
        W = w_qkv; WT = wqkvT; N = QKV_N;
        n0 = (b2 % 192) * 32; k0 = (b2 / 192) * 32;
    } else {
        const int b3 = bid - 14336;
        W = w_o; WT = woT; N = DMODEL;
        n0 = (b3 % 64) * 32; k0 = (b3 / 64) * 32;
    }
    const int tx = threadIdx.x & 31, ty = threadIdx.x >> 5;
    #pragma unroll
    for (int i = 0; i < 4; i++) {
        int kk = ty + i * 8;
        tile[kk][tx] = W[(size_t)(k0 + kk) * N + n0 + tx];
    }
    __syncthreads();
    #pragma unroll
    for (int i = 0; i < 4; i++) {
        int nn = ty + i * 8;
        WT[(size_t)(n0 + nn) * DMODEL + k0 + tx] = (bf16)tile[tx][nn];
    }
}

// ---------------------------------------------------------------------------
// gemm256 (r9 champion, 2D grid — XCD swizzle REFUTED r14: operands L3-fit,
// FETCH rose 618->643MB and dur +2µs; T1 needs HBM-bound regime).
// 256x256 tile, BK=32, 512 thr, phase-split read-ahead, counted vmcnt(4),
// swizzled LDS (0 conflicts). 1001 TF, MfmaUtil 45.6%.
// ---------------------------------------------------------------------------
template<bool CBF16>
__global__ __launch_bounds__(512, 2) void gemm256(const bf16* __restrict__ A,
                                                  const bf16* __restrict__ BT,
                                                  void* __restrict__ Cptr, int Ndim)
{
    constexpr int K = DMODEL;
    constexpr int NT = K / 32;
    __shared__ __align__(16) bf16 a_sm[2][256*32];
    __shared__ __align__(16) bf16 b_sm[2][256*32];

    const int tid = threadIdx.x;
    const int l = tid & 63, wid = tid >> 6;
    const int wm = wid >> 2, wn = wid & 3;
    const int brow = blockIdx.x * 256, bcol = blockIdx.y * 256;
    const int l15 = l & 15, lg = l >> 4;

    const int st_mr  = tid >> 3;
    const int st_s0  = (tid & 7) ^ (st_mr & 7);
    const int st_row = 2 * st_mr + (st_s0 >> 2);
    const int st_col = (st_s0 & 3) << 3;
    const bf16* Asrc = A  + (size_t)(brow + st_row) * K + st_col;
    const bf16* Bsrc = BT + (size_t)(bcol + st_row) * K + st_col;

    int aoff[8], boff[4];
    #pragma unroll
    for (int mi = 0; mi < 8; mi++) {
        const int r = wm*128 + mi*16 + l15, mr = r >> 1;
        aoff[mi] = mr*64 + ((((( r & 1) << 2) | lg) ^ (mr & 7)) << 3);
    }
    #pragma unroll
    for (int ni = 0; ni < 4; ni++) {
        const int r = wn*64 + ni*16 + l15, mr = r >> 1;
        boff[ni] = mr*64 + ((((( r & 1) << 2) | lg) ^ (mr & 7)) << 3);
    }

    f32x4 acc[8][4];
    #pragma unroll
    for (int mi = 0; mi < 8; mi++)
        #pragma unroll
        for (int ni = 0; ni < 4; ni++)
            #pragma unroll
            for (int e = 0; e < 4; e++) acc[mi][ni][e] = 0.f;

    auto STAGE = [&](int buf, int kt2) {
        const int k0 = kt2 * 32;
        #pragma unroll
        for (int i = 0; i < 2; i++) {
            gload_lds16(Asrc + (size_t)(i*128) * K + k0, &a_sm[buf][i*4096 + tid*8]);
            gload_lds16(Bsrc + (size_t)(i*128) * K + k0, &b_sm[buf][i*4096 + tid*8]);
        }
    };

    bf16x8 af[4], ag[4], bfr[4];
    auto READ0 = [&](int buf) {
        #pragma unroll
        for (int mi = 0; mi < 4; mi++) af[mi]  = *(const bf16x8*)&a_sm[buf][aoff[mi]];
        #pragma unroll
        for (int ni = 0; ni < 4; ni++) bfr[ni] = *(const bf16x8*)&b_sm[buf][boff[ni]];
    };
    auto READ1 = [&](int buf) {
        #pragma unroll
        for (int mi = 0; mi < 4; mi++) ag[mi] = *(const bf16x8*)&a_sm[buf][aoff[4 + mi]];
    };
    auto MFMA_LO = [&]() {
        __builtin_amdgcn_s_setprio(1);
        #pragma unroll
        for (int mi = 0; mi < 4; mi++)
            #pragma unroll
            for (int ni = 0; ni < 4; ni++)
                acc[mi][ni] = mfma16x16x32(af[mi], bfr[ni], acc[mi][ni]);
        __builtin_amdgcn_s_setprio(0);
    };
    auto MFMA_HI = [&]() {
        __builtin_amdgcn_s_setprio(1);
        #pragma unroll
        for (int mi = 0; mi < 4; mi++)
            #pragma unroll
            for (int ni = 0; ni < 4; ni++)
                acc[4 + mi][ni] = mfma16x16x32(ag[mi], bfr[ni], acc[4 + mi][ni]);
        __builtin_amdgcn_s_setprio(0);
    };

    STAGE(0, 0);
    STAGE(1, 1);
    asm volatile("s_waitcnt vmcnt(4)" ::: "memory");
    __builtin_amdgcn_sched_barrier(0);
    __builtin_amdgcn_s_barrier();
    READ0(0);

    for (int tp = 0; tp < NT - 2; tp += 2) {
        READ1(0);
        __builtin_amdgcn_sched_barrier(0);
        MFMA_LO();
        asm volatile("s_waitcnt lgkmcnt(0)" ::: "memory");
        __builtin_amdgcn_sched_barrier(0);
        __builtin_amdgcn_s_barrier();
        STAGE(0, tp + 2);
        __builtin_amdgcn_sched_barrier(0);
        MFMA_HI();
        asm volatile("s_waitcnt vmcnt(4)" ::: "memory");
        __builtin_amdgcn_sched_barrier(0);
        __builtin_amdgcn_s_barrier();

        READ0(1);
        READ1(1);
        __builtin_amdgcn_sched_barrier(0);
        MFMA_LO();
        asm volatile("s_waitcnt lgkmcnt(0)" ::: "memory");
        __builtin_amdgcn_sched_barrier(0);
        __builtin_amdgcn_s_barrier();
        STAGE(1, tp + 3);
        __builtin_amdgcn_sched_barrier(0);
        MFMA_HI();
        asm volatile("s_waitcnt vmcnt(4)" ::: "memory");
        __builtin_amdgcn_sched_barrier(0);
        __builtin_amdgcn_s_barrier();
        READ0(0);
    }

    READ1(0);
    __builtin_amdgcn_sched_barrier(0);
    MFMA_LO();
    asm volatile("s_waitcnt lgkmcnt(0)" ::: "memory");
    __builtin_amdgcn_sched_barrier(0);
    MFMA_HI();
    asm volatile("s_waitcnt vmcnt(0)" ::: "memory");
    __builtin_amdgcn_sched_barrier(0);
    __builtin_amdgcn_s_barrier();
    READ0(1);
    READ1(1);
    __builtin_amdgcn_sched_barrier(0);
    MFMA_LO();
    asm volatile("s_waitcnt lgkmcnt(0)" ::: "memory");
    __builtin_amdgcn_sched_barrier(0);
    MFMA_HI();

    #pragma unroll
    for (int mi = 0; mi < 8; mi++)
        #pragma unroll
        for (int ni = 0; ni < 4; ni++) {
            const int row = brow + wm*128 + mi*16 + lg*4;
            const int col = bcol + wn*64 + ni*16 + l15;
            #pragma unroll
            for (int j = 0; j < 4; j++) {
                float v = acc[mi][ni][j];
                if (CBF16) ((bf16*)Cptr)[(size_t)(row + j) * Ndim + col] = (bf16)v;
                else       ((float*)Cptr)[(size_t)(row + j) * Ndim + col] = v;
            }
        }
}

// ---------------------------------------------------------------------------
// attn_local (fused): lob = (1-g)*local_out; ksum[bh,n,dk] = sum_s elu1(k);
// Ub[seg] = skT @ v.
// ---------------------------------------------------------------------------
__global__ void attn_local(const bf16* __restrict__ qkv,
                           bf16* __restrict__ lob,
                           const float* __restrict__ bal,
                           float* __restrict__ ksum,
                           bf16* __restrict__ Ub)
{
    __shared__ bf16 qp_sm [128*136];
    __shared__ bf16 k_sm  [128*136];
    __shared__ bf16 vT_sm [128*136];
    __shared__ bf16 skT_sm[128*136];
    const int bid = blockIdx.x;
    const int h = bid & 15, b = (bid >> 4) & 1, n = bid >> 5;
    const int bh = b*NHEADS + h;
    const int tid = threadIdx.x, l = tid & 63, w = tid >> 6;
    const int l15 = l & 15, lk = (l >> 4) * 8, r0 = (l >> 4) * 4;
    const float g  = 1.f / (1.f + __expf(-bal[h]));
    const float w1 = 1.f - g;

    {
        const int srow = tid >> 1, off = (tid & 1) << 6;
        const size_t gb = ((size_t)(n*SEGLEN + srow)*NBATCH + b)*QKV_N + h*DHEAD + off;
        const bf16* qsrc = qkv + gb;
        const bf16* ksrc = qkv + gb + DMODEL;
        const bf16* vsrc = qkv + gb + 2*DMODEL;
        #pragma unroll
        for (int j = 0; j < 64; j += 8) {
            bf16x8 kv = *(const bf16x8*)(ksrc + j);
            bf16x8 vv = *(const bf16x8*)(vsrc + j);
            *(bf16x8*)&qp_sm[srow*136 + off + j] = *(const bf16x8*)(qsrc + j);
            *(bf16x8*)&k_sm [srow*136 + off + j] = kv;
            #pragma unroll
            for (int e = 0; e < 8; e++) {
                vT_sm [(off + j + e)*136 + srow] = vv[e];
                skT_sm[(off + j + e)*136 + srow] = (bf16)elu1((float)kv[e]);
            }
        }
    }
    __syncthreads();

    f32x4 sc[2][8];
    for (int mi = 0; mi < 2; mi++) for (int ni = 0; ni < 8; ni++)
        for (int e = 0; e < 4; e++) sc[mi][ni][e] = 0.f;
    #pragma unroll
    for (int ks = 0; ks < 4; ks++) {
        const int ko = ks*32 + lk;
        bf16x8 aq[2], bk[8];
        #pragma unroll
        for (int mi = 0; mi < 2; mi++)
            aq[mi] = *(const bf16x8*)&qp_sm[(w*32 + mi*16 + l15)*136 + ko];
        #pragma unroll
        for (int ni = 0; ni < 8; ni++)
            bk[ni] = *(const bf16x8*)&k_sm[(ni*16 + l15)*136 + ko];
        #pragma unroll
        for (int mi = 0; mi < 2; mi++)
            #pragma unroll
            for (int ni = 0; ni < 8; ni++)
                sc[mi][ni] = mfma16x16x32(aq[mi], bk[ni], sc[mi][ni]);
    }
    __syncthreads();

    const float scale = 0.088388347648318433f;
    #pragma unroll
    for (int mi = 0; mi < 2; mi++) {
        #pragma unroll
        for (int j = 0; j < 4; j++) {
            const int R = w*32 + mi*16 + r0 + j;
            float v[8]; float mx = -1e30f;
            #pragma unroll
            for (int ni = 0; ni < 8; ni++) {
                float x = sc[mi][ni][j] * scale;
                if (ni*16 + l15 > R) x = -1e9f;
                v[ni] = x; mx = fmaxf(mx, x);
            }
            #pragma unroll
            for (int d = 1; d < 16; d <<= 1) mx = fmaxf(mx, __shfl_xor(mx, d));
            float sum = 0.f;
            #pragma unroll
            for (int ni = 0; ni < 8; ni++) { v[ni] = __expf(v[ni] - mx); sum += v[ni]; }
            #pragma unroll
            for (int d = 1; d < 16; d <<= 1) sum += __shfl_xor(sum, d);
            const float inv = 1.f / sum;
            #pragma unroll
            for (int ni = 0; ni < 8; ni++)
                qp_sm[R*136 + ni*16 + l15] = (bf16)(v[ni] * inv);
        }
    }
    __syncthreads();

    f32x4 o[2][8];
    for (int mi = 0; mi < 2; mi++) for (int ni = 0; ni < 8; ni++)
        for (int e = 0; e < 4; e++) o[mi][ni][e] = 0.f;
    #pragma unroll
    for (int ks = 0; ks < 4; ks++) {
        const int ko = ks*32 + lk;
        bf16x8 ap[2], bv[8];
        #pragma unroll
        for (int mi = 0; mi < 2; mi++)
            ap[mi] = *(const bf16x8*)&qp_sm[(w*32 + mi*16 + l15)*136 + ko];
        #pragma unroll
        for (int ni = 0; ni < 8; ni++)
            bv[ni] = *(const bf16x8*)&vT_sm[(ni*16 + l15)*136 + ko];
        #pragma unroll
        for (int mi = 0; mi < 2; mi++)
            #pragma unroll
            for (int ni = 0; ni < 8; ni++)
                o[mi][ni] = mfma16x16x32(ap[mi], bv[ni], o[mi][ni]);
    }

    #pragma unroll
    for (int mi = 0; mi < 2; mi++)
        #pragma unroll
        for (int ni = 0; ni < 8; ni++) {
            const int R = w*32 + mi*16 + r0;
            const int c = ni*16 + l15;
            #pragma unroll
            for (int j = 0; j < 4; j++)
                lob[((size_t)(n*SEGLEN + R + j)*NBATCH + b)*DMODEL + h*DHEAD + c] =
                    (bf16)(w1 * o[mi][ni][j]);
        }

    if (tid < 128) {
        float a = 0.f;
        const bf16* row = &skT_sm[tid*136];
        #pragma unroll
        for (int ss = 0; ss < 128; ss += 8) {
            bf16x8 v8 = *(const bf16x8*)(row + ss);
            #pragma unroll
            for (int e = 0; e < 8; e++) a += (float)v8[e];
        }
        ksum[((size_t)bh*NSEG + n)*128 + tid] = a;
    }

    {
        const int wr = w >> 1, wc = w & 1;
        const size_t seg = (size_t)bh*NSEG + n;
        f32x4 ua[4][4];
        for (int mi = 0; mi < 4; mi++) for (int ni = 0; ni < 4; ni++)
            for (int e = 0; e < 4; e++) ua[mi][ni][e] = 0.f;
        #pragma unroll
        for (int ks = 0; ks < 4; ks++) {
            const int ko = ks*32 + lk;
            bf16x8 auf[4], bv[4];
            #pragma unroll
            for (int mi = 0; mi < 4; mi++)
                auf[mi] = *(const bf16x8*)&skT_sm[(wr*64 + mi*16 + l15)*136 + ko];
            #pragma unroll
            for (int ni = 0; ni < 4; ni++)
                bv[ni] = *(const bf16x8*)&vT_sm[(wc*64 + ni*16 + l15)*136 + ko];
            #pragma unroll
            for (int mi = 0; mi < 4; mi++)
                #pragma unroll
                for (int ni = 0; ni < 4; ni++)
                    ua[mi][ni] = mfma16x16x32(auf[mi], bv[ni], ua[mi][ni]);
        }
        #pragma unroll
        for (int mi = 0; mi < 4; mi++)
            #pragma unroll
            for (int ni = 0; ni < 4; ni++) {
                const int row = wr*64 + mi*16 + r0, col = wc*64 + ni*16 + l15;
                #pragma unroll
                for (int j = 0; j < 4; j++)
                    Ub[(seg << 14) + (size_t)(row + j)*128 + col] = (bf16)ua[mi][ni][j];
            }
    }
}

// ---------------------------------------------------------------------------
// scan2: mem_n = mem_{n-1} - skT@((sk@mem_{n-1})/denk) + U_n ;
//        retr  = (sq@mem_{n-1})/denq ; lob += g*retr.
// Norm prefix in registers. Grid 256, XCD-locality decode bh=bid&31.
// ---------------------------------------------------------------------------
__global__ __launch_bounds__(256, 1) void scan2(const bf16* __restrict__ qkv,
                                                const bf16* __restrict__ Ub,
                                                const float* __restrict__ ksum,
                                                bf16* __restrict__ lob,
                                                const float* __restrict__ bal)
{
    __shared__ bf16 memT[16*136];
    __shared__ bf16 skT [128*136];
    __shared__ bf16 yT  [16*136];
    const int bid = blockIdx.x;
    const int bh = bid & 31, dq = bid >> 5;
    const int b = bh >> 4, h = bh & 15;
    const int tid = threadIdx.x, l = tid & 63, w = tid >> 6;
    const int l15 = l & 15, lk = (l >> 4) * 8, r0 = (l >> 4) * 4;
    const float g = 1.f / (1.f + __expf(-bal[h]));
    const size_t segb = (size_t)bh * NSEG;
    const int cdv = dq*16 + l15;

    float mast[2][4];
    #pragma unroll
    for (int mi = 0; mi < 2; mi++)
        #pragma unroll
        for (int j = 0; j < 4; j++) {
            const int row = w*32 + mi*16 + r0 + j;
            mast[mi][j] = (float)Ub[(segb << 14) + (size_t)row*128 + cdv];
            memT[l15*136 + row] = (bf16)mast[mi][j];
        }
    __syncthreads();

    float nrm[4][8];
    {
        const float* np = ksum + segb*128;
        #pragma unroll
        for (int ks = 0; ks < 4; ks++) {
            float4 a0 = *(const float4*)(np + ks*32 + lk);
            float4 a1 = *(const float4*)(np + ks*32 + lk + 4);
            nrm[ks][0]=a0.x; nrm[ks][1]=a0.y; nrm[ks][2]=a0.z; nrm[ks][3]=a0.w;
            nrm[ks][4]=a1.x; nrm[ks][5]=a1.y; nrm[ks][6]=a1.z; nrm[ks][7]=a1.w;
        }
    }

    bf16x8 qA[8], kA[8], qB[8], kB[8];

    auto loadraw = [&](int n2, bf16x8* qr, bf16x8* kr) {
        #pragma unroll
        for (int mi = 0; mi < 2; mi++)
            #pragma unroll
            for (int ks = 0; ks < 4; ks++) {
                const size_t base =
                    ((size_t)(n2*SEGLEN + w*32 + mi*16 + l15)*NBATCH + b)*QKV_N
                    + h*DHEAD + ks*32 + lk;
                qr[mi*4 + ks] = *(const bf16x8*)(qkv + base);
                kr[mi*4 + ks] = *(const bf16x8*)(qkv + base + DMODEL);
            }
    };

    auto step = [&](int n, bf16x8* curq, bf16x8* curk, bf16x8* nxtq, bf16x8* nxtk) {
        float uval[2][4], lv[2][4];
        #pragma unroll
        for (int mi = 0; mi < 2; mi++)
            #pragma unroll
            for (int j = 0; j < 4; j++) {
                const int sx = w*32 + mi*16 + r0 + j;
                uval[mi][j] = (float)Ub[((segb + n) << 14) + (size_t)sx*128 + cdv];
                lv[mi][j] = (float)lob[((size_t)(n*SEGLEN + sx)*NBATCH + b)*DMODEL
                                       + h*DHEAD + cdv];
            }
        bf16x8 sqf[8], skf[8];
        #pragma unroll
        for (int f = 0; f < 8; f++) {
            bf16x8 qv = curq[f], kv = curk[f], sq_, sk_;
            #pragma unroll
            for (int e = 0; e < 8; e++) {
                sq_[e] = (bf16)elu1((float)qv[e]);
                sk_[e] = (bf16)elu1((float)kv[e]);
            }
            sqf[f] = sq_; skf[f] = sk_;
        }
        float dqv[2][4], ivk[2][4];
        #pragma unroll
        for (int mi = 0; mi < 2; mi++) {
            float aq = 0.f, ak = 0.f;
            #pragma unroll
            for (int ks = 0; ks < 4; ks++)
                #pragma unroll
                for (int e = 0; e < 8; e++) {
                    aq += (float)sqf[mi*4 + ks][e] * nrm[ks][e];
                    ak += (float)skf[mi*4 + ks][e] * nrm[ks][e];
                }
            aq += __shfl_xor(aq, 16); aq += __shfl_xor(aq, 32);
            ak += __shfl_xor(ak, 16); ak += __shfl_xor(ak, 32);
            #pragma unroll
            for (int j = 0; j < 4; j++) {
                dqv[mi][j] = __shfl(aq, r0 + j);
                ivk[mi][j] = 1.f / __shfl(ak, r0 + j);
            }
        }
        {
            const float* np = ksum + (segb + n)*128;
            #pragma unroll
            for (int ks = 0; ks < 4; ks++) {
                float4 a0 = *(const float4*)(np + ks*32 + lk);
                float4 a1 = *(const float4*)(np + ks*32 + lk + 4);
                nrm[ks][0]+=a0.x; nrm[ks][1]+=a0.y; nrm[ks][2]+=a0.z; nrm[ks][3]+=a0.w;
                nrm[ks][4]+=a1.x; nrm[ks][5]+=a1.y; nrm[ks][6]+=a1.z; nrm[ks][7]+=a1.w;
            }
        }
        #pragma unroll
        for (int mi = 0; mi < 2; mi++)
            #pragma unroll
            for (int ks = 0; ks < 4; ks++)
                #pragma unroll
                for (int e = 0; e < 8; e++)
                    skT[(ks*32 + lk + e)*136 + w*32 + mi*16 + l15] = skf[mi*4 + ks][e];
        f32x4 racc[2], yacc[2];
        #pragma unroll
        for (int mi = 0; mi < 2; mi++)
            #pragma unroll
            for (int e = 0; e < 4; e++) { racc[mi][e] = 0.f; yacc[mi][e] = 0.f; }
        #pragma unroll
        for (int ks = 0; ks < 4; ks++) {
            bf16x8 bm = *(const bf16x8*)&memT[l15*136 + ks*32 + lk];
            #pragma unroll
            for (int mi = 0; mi < 2; mi++) {
                racc[mi] = mfma16x16x32(sqf[mi*4 + ks], bm, racc[mi]);
                yacc[mi] = mfma16x16x32(skf[mi*4 + ks], bm, yacc[mi]);
            }
        }
        if (n < NSEG - 1) loadraw(n + 1, nxtq, nxtk);
        #pragma unroll
        for (int mi = 0; mi < 2; mi++)
            #pragma unroll
            for (int j = 0; j < 4; j++)
                yT[l15*136 + w*32 + mi*16 + r0 + j] = (bf16)(yacc[mi][j] * ivk[mi][j]);
        __syncthreads();
        f32x4 zacc[2];
        #pragma unroll
        for (int mi = 0; mi < 2; mi++)
            #pragma unroll
            for (int e = 0; e < 4; e++) zacc[mi][e] = 0.f;
        #pragma unroll
        for (int ks = 0; ks < 4; ks++) {
            bf16x8 bz = *(const bf16x8*)&yT[l15*136 + ks*32 + lk];
            #pragma unroll
            for (int mi = 0; mi < 2; mi++) {
                bf16x8 az = *(const bf16x8*)&skT[(w*32 + mi*16 + l15)*136 + ks*32 + lk];
                zacc[mi] = mfma16x16x32(az, bz, zacc[mi]);
            }
        }
        #pragma unroll
        for (int mi = 0; mi < 2; mi++)
            #pragma unroll
            for (int j = 0; j < 4; j++) {
                const int sx = w*32 + mi*16 + r0 + j;
                const float rv = racc[mi][j] / dqv[mi][j];
                lob[((size_t)(n*SEGLEN + sx)*NBATCH + b)*DMODEL + h*DHEAD + cdv] =
                    (bf16)(lv[mi][j] + g * rv);
                mast[mi][j] += uval[mi][j] - zacc[mi][j];
                memT[l15*136 + sx] = (bf16)mast[mi][j];
            }
        __syncthreads();
    };

    loadraw(1, qA, kA);
    for (int n = 1; n < NSEG; n += 2) {
        step(n, qA, kA, qB, kB);
        if (n + 1 < NSEG) step(n + 1, qB, kB, qA, kA);
    }
}

// ---------------------------------------------------------------------------
// Workspace layout (max 295,698,432 B, proven-safe):
//   [0)            qkvb  157,286,400
//   [157,286,400)  lob    52,428,800
//   [209,715,200)  woT     8,388,608
//   [218,103,808)  abf    52,428,800   -> reused as Ub (bf16) after QKV GEMM
//   [270,532,608)  wqkvT  25,165,824   -> reused as ksum
// ---------------------------------------------------------------------------
extern "C" void kernel_launch(void* const* d_in, const int* in_sizes, int n_in,
                              void* d_out, int out_size, void* d_ws, size_t ws_size,
                              hipStream_t stream)
{
    (void)in_sizes; (void)n_in; (void)out_size; (void)ws_size;
    const float* hidden = (const float*)d_in[0];
    const float* w_qkv  = (const float*)d_in[2];
    const float* w_o    = (const float*)d_in[3];
    const float* bal    = (const float*)d_in[4];

    char* ws = (char*)d_ws;
    bf16*  qkvb  = (bf16*)ws;
    bf16*  lob   = (bf16*)(ws + 157286400);
    bf16*  woT   = (bf16*)(ws + 209715200);
    bf16*  abf   = (bf16*)(ws + 218103808);
    bf16*  Ub    = abf;
    bf16*  wqkvT = (bf16*)(ws + 270532608);
    float* ksum  = (float*)(ws + 270532608);

    dim3 blk(256);
    prep_inputs<<<18432, blk, 0, stream>>>(hidden, abf, w_qkv, wqkvT, w_o, woT);

    gemm256<true><<<dim3(MROWS/256, QKV_N/256), 512, 0, stream>>>(abf, wqkvT, qkvb, QKV_N);

    attn_local<<<dim3(NSEG*NBATCH*NHEADS), blk, 0, stream>>>(qkvb, lob, bal, ksum, Ub);
    scan2<<<256, blk, 0, stream>>>(qkvb, Ub, ksum, lob, bal);

    gemm256<false><<<dim3(MROWS/256, DMODEL/256), 512, 0, stream>>>(lob, woT, d_out, DMODEL);
}

// Round 16
// 831.218 us; speedup vs baseline: 1.0615x; 1.0481x over previous
//
#include <hip/hip_runtime.h>
#include <hip/hip_bf16.h>

typedef __bf16 bf16;
typedef __bf16 bf16x8 __attribute__((ext_vector_type(8)));
typedef __bf16 bf16x4 __attribute__((ext_vector_type(4)));
typedef float  f32x4  __attribute__((ext_vector_type(4)));

#define S_LEN   6400
#define NBATCH  2
#define DMODEL  2048
#define NHEADS  16
#define DHEAD   128
#define NSEG    50
#define SEGLEN  128
#define MROWS   (S_LEN*NBATCH)     // 12800
#define QKV_N   (3*DMODEL)         // 6144

static __device__ __forceinline__ f32x4 mfma16x16x32(bf16x8 a, bf16x8 b, f32x4 c) {
    return __builtin_amdgcn_mfma_f32_16x16x32_bf16(a, b, c, 0, 0, 0);
}
static __device__ __forceinline__ void gload_lds16(const bf16* g, bf16* l) {
    __builtin_amdgcn_global_load_lds(
        (const __attribute__((address_space(1))) void*)g,
        (__attribute__((address_space(3))) void*)l, 16, 0, 0);
}
static __device__ __forceinline__ float elu1(float x) {
    return x > 0.f ? x + 1.f : __expf(x);
}

// ---------------------------------------------------------------------------
// prep_inputs: one launch for {fp32->bf16 hidden, W_qkv^T, W_o^T}.
// ---------------------------------------------------------------------------
__global__ void prep_inputs(const float* __restrict__ hidden, bf16* __restrict__ abf,
                            const float* __restrict__ w_qkv, bf16* __restrict__ wqkvT,
                            const float* __restrict__ w_o,   bf16* __restrict__ woT)
{
    __shared__ float tile[32][33];
    const int bid = blockIdx.x;
    if (bid < 2048) {
        const int n8 = MROWS*DMODEL/8;
        const int stride = 2048 * 256;
        for (int i = bid * 256 + threadIdx.x; i < n8; i += stride) {
            const float4* p = (const float4*)(hidden + (size_t)i * 8);
            float4 v0 = p[0], v1 = p[1];
            bf16x8 o;
            o[0]=(bf16)v0.x; o[1]=(bf16)v0.y; o[2]=(bf16)v0.z; o[3]=(bf16)v0.w;
            o[4]=(bf16)v1.x; o[5]=(bf16)v1.y; o[6]=(bf16)v1.z; o[7]=(bf16)v1.w;
            *(bf16x8*)(abf + (size_t)i * 8) = o;
        }
        return;
    }
    const float* W; bf16* WT; int N, n0, k0;
    if (bid < 14336) {
        const int b2 = bid - 2048;
        W = w_qkv; WT = wqkvT; N = QKV_N;
        n0 = (b2 % 192) * 32; k0 = (b2 / 192) * 32;
    } else {
        const int b3 = bid - 14336;
        W = w_o; WT = woT; N = DMODEL;
        n0 = (b3 % 64) * 32; k0 = (b3 / 64) * 32;
    }
    const int tx = threadIdx.x & 31, ty = threadIdx.x >> 5;
    #pragma unroll
    for (int i = 0; i < 4; i++) {
        int kk = ty + i * 8;
        tile[kk][tx] = W[(size_t)(k0 + kk) * N + n0 + tx];
    }
    __syncthreads();
    #pragma unroll
    for (int i = 0; i < 4; i++) {
        int nn = ty + i * 8;
        WT[(size_t)(n0 + nn) * DMODEL + k0 + tx] = (bf16)tile[tx][nn];
    }
}

// ---------------------------------------------------------------------------
// gemm256 (r9 champion, 2D grid — XCD swizzle REFUTED r14: operands L3-fit).
// 256x256 tile, BK=32, 512 thr, phase-split read-ahead, counted vmcnt(4),
// swizzled LDS (0 conflicts). 1001 TF, MfmaUtil 45.6%.
// ---------------------------------------------------------------------------
template<bool CBF16>
__global__ __launch_bounds__(512, 2) void gemm256(const bf16* __restrict__ A,
                                                  const bf16* __restrict__ BT,
                                                  void* __restrict__ Cptr, int Ndim)
{
    constexpr int K = DMODEL;
    constexpr int NT = K / 32;
    __shared__ __align__(16) bf16 a_sm[2][256*32];
    __shared__ __align__(16) bf16 b_sm[2][256*32];

    const int tid = threadIdx.x;
    const int l = tid & 63, wid = tid >> 6;
    const int wm = wid >> 2, wn = wid & 3;
    const int brow = blockIdx.x * 256, bcol = blockIdx.y * 256;
    const int l15 = l & 15, lg = l >> 4;

    const int st_mr  = tid >> 3;
    const int st_s0  = (tid & 7) ^ (st_mr & 7);
    const int st_row = 2 * st_mr + (st_s0 >> 2);
    const int st_col = (st_s0 & 3) << 3;
    const bf16* Asrc = A  + (size_t)(brow + st_row) * K + st_col;
    const bf16* Bsrc = BT + (size_t)(bcol + st_row) * K + st_col;

    int aoff[8], boff[4];
    #pragma unroll
    for (int mi = 0; mi < 8; mi++) {
        const int r = wm*128 + mi*16 + l15, mr = r >> 1;
        aoff[mi] = mr*64 + ((((( r & 1) << 2) | lg) ^ (mr & 7)) << 3);
    }
    #pragma unroll
    for (int ni = 0; ni < 4; ni++) {
        const int r = wn*64 + ni*16 + l15, mr = r >> 1;
        boff[ni] = mr*64 + ((((( r & 1) << 2) | lg) ^ (mr & 7)) << 3);
    }

    f32x4 acc[8][4];
    #pragma unroll
    for (int mi = 0; mi < 8; mi++)
        #pragma unroll
        for (int ni = 0; ni < 4; ni++)
            #pragma unroll
            for (int e = 0; e < 4; e++) acc[mi][ni][e] = 0.f;

    auto STAGE = [&](int buf, int kt2) {
        const int k0 = kt2 * 32;
        #pragma unroll
        for (int i = 0; i < 2; i++) {
            gload_lds16(Asrc + (size_t)(i*128) * K + k0, &a_sm[buf][i*4096 + tid*8]);
            gload_lds16(Bsrc + (size_t)(i*128) * K + k0, &b_sm[buf][i*4096 + tid*8]);
        }
    };

    bf16x8 af[4], ag[4], bfr[4];
    auto READ0 = [&](int buf) {
        #pragma unroll
        for (int mi = 0; mi < 4; mi++) af[mi]  = *(const bf16x8*)&a_sm[buf][aoff[mi]];
        #pragma unroll
        for (int ni = 0; ni < 4; ni++) bfr[ni] = *(const bf16x8*)&b_sm[buf][boff[ni]];
    };
    auto READ1 = [&](int buf) {
        #pragma unroll
        for (int mi = 0; mi < 4; mi++) ag[mi] = *(const bf16x8*)&a_sm[buf][aoff[4 + mi]];
    };
    auto MFMA_LO = [&]() {
        __builtin_amdgcn_s_setprio(1);
        #pragma unroll
        for (int mi = 0; mi < 4; mi++)
            #pragma unroll
            for (int ni = 0; ni < 4; ni++)
                acc[mi][ni] = mfma16x16x32(af[mi], bfr[ni], acc[mi][ni]);
        __builtin_amdgcn_s_setprio(0);
    };
    auto MFMA_HI = [&]() {
        __builtin_amdgcn_s_setprio(1);
        #pragma unroll
        for (int mi = 0; mi < 4; mi++)
            #pragma unroll
            for (int ni = 0; ni < 4; ni++)
                acc[4 + mi][ni] = mfma16x16x32(ag[mi], bfr[ni], acc[4 + mi][ni]);
        __builtin_amdgcn_s_setprio(0);
    };

    STAGE(0, 0);
    STAGE(1, 1);
    asm volatile("s_waitcnt vmcnt(4)" ::: "memory");
    __builtin_amdgcn_sched_barrier(0);
    __builtin_amdgcn_s_barrier();
    READ0(0);

    for (int tp = 0; tp < NT - 2; tp += 2) {
        READ1(0);
        __builtin_amdgcn_sched_barrier(0);
        MFMA_LO();
        asm volatile("s_waitcnt lgkmcnt(0)" ::: "memory");
        __builtin_amdgcn_sched_barrier(0);
        __builtin_amdgcn_s_barrier();
        STAGE(0, tp + 2);
        __builtin_amdgcn_sched_barrier(0);
        MFMA_HI();
        asm volatile("s_waitcnt vmcnt(4)" ::: "memory");
        __builtin_amdgcn_sched_barrier(0);
        __builtin_amdgcn_s_barrier();

        READ0(1);
        READ1(1);
        __builtin_amdgcn_sched_barrier(0);
        MFMA_LO();
        asm volatile("s_waitcnt lgkmcnt(0)" ::: "memory");
        __builtin_amdgcn_sched_barrier(0);
        __builtin_amdgcn_s_barrier();
        STAGE(1, tp + 3);
        __builtin_amdgcn_sched_barrier(0);
        MFMA_HI();
        asm volatile("s_waitcnt vmcnt(4)" ::: "memory");
        __builtin_amdgcn_sched_barrier(0);
        __builtin_amdgcn_s_barrier();
        READ0(0);
    }

    READ1(0);
    __builtin_amdgcn_sched_barrier(0);
    MFMA_LO();
    asm volatile("s_waitcnt lgkmcnt(0)" ::: "memory");
    __builtin_amdgcn_sched_barrier(0);
    MFMA_HI();
    asm volatile("s_waitcnt vmcnt(0)" ::: "memory");
    __builtin_amdgcn_sched_barrier(0);
    __builtin_amdgcn_s_barrier();
    READ0(1);
    READ1(1);
    __builtin_amdgcn_sched_barrier(0);
    MFMA_LO();
    asm volatile("s_waitcnt lgkmcnt(0)" ::: "memory");
    __builtin_amdgcn_sched_barrier(0);
    MFMA_HI();

    #pragma unroll
    for (int mi = 0; mi < 8; mi++)
        #pragma unroll
        for (int ni = 0; ni < 4; ni++) {
            const int row = brow + wm*128 + mi*16 + lg*4;
            const int col = bcol + wn*64 + ni*16 + l15;
            #pragma unroll
            for (int j = 0; j < 4; j++) {
                float v = acc[mi][ni][j];
                if (CBF16) ((bf16*)Cptr)[(size_t)(row + j) * Ndim + col] = (bf16)v;
                else       ((float*)Cptr)[(size_t)(row + j) * Ndim + col] = v;
            }
        }
}

// ---------------------------------------------------------------------------
// attn_local (fused): lob = (1-g)*local_out; ksum[bh,n,dk] = sum_s elu1(k);
// Ub[seg] = skT @ v. NEW (r16): overwrites q/k in qkvb IN PLACE with
// sq=elu1(q), sk=elu1(k) — raw q/k are dead after this kernel; scan2 then
// consumes elu'd values directly (its dominant VALU cost removed). Each block
// owns its (n,b,h) slice exclusively -> race-free; qkvb fully regenerated by
// gemm256 each replay -> graph-deterministic.
// ---------------------------------------------------------------------------
__global__ void attn_local(bf16* __restrict__ qkv,
                           bf16* __restrict__ lob,
                           const float* __restrict__ bal,
                           float* __restrict__ ksum,
                           bf16* __restrict__ Ub)
{
    __shared__ bf16 qp_sm [128*136];
    __shared__ bf16 k_sm  [128*136];
    __shared__ bf16 vT_sm [128*136];
    __shared__ bf16 skT_sm[128*136];
    const int bid = blockIdx.x;
    const int h = bid & 15, b = (bid >> 4) & 1, n = bid >> 5;
    const int bh = b*NHEADS + h;
    const int tid = threadIdx.x, l = tid & 63, w = tid >> 6;
    const int l15 = l & 15, lk = (l >> 4) * 8, r0 = (l >> 4) * 4;
    const float g  = 1.f / (1.f + __expf(-bal[h]));
    const float w1 = 1.f - g;

    {
        const int srow = tid >> 1, off = (tid & 1) << 6;
        const size_t gb = ((size_t)(n*SEGLEN + srow)*NBATCH + b)*QKV_N + h*DHEAD + off;
        bf16* qsrc = qkv + gb;
        bf16* ksrc = qkv + gb + DMODEL;
        const bf16* vsrc = qkv + gb + 2*DMODEL;
        #pragma unroll
        for (int j = 0; j < 64; j += 8) {
            bf16x8 qv = *(const bf16x8*)(qsrc + j);
            bf16x8 kv = *(const bf16x8*)(ksrc + j);
            bf16x8 vv = *(const bf16x8*)(vsrc + j);
            bf16x8 sqv, skv;
            #pragma unroll
            for (int e = 0; e < 8; e++) {
                sqv[e] = (bf16)elu1((float)qv[e]);
                skv[e] = (bf16)elu1((float)kv[e]);
            }
            *(bf16x8*)&qp_sm[srow*136 + off + j] = qv;
            *(bf16x8*)&k_sm [srow*136 + off + j] = kv;
            #pragma unroll
            for (int e = 0; e < 8; e++) {
                vT_sm [(off + j + e)*136 + srow] = vv[e];
                skT_sm[(off + j + e)*136 + srow] = skv[e];
            }
            *(bf16x8*)(qsrc + j) = sqv;   // in-place elu for scan2
            *(bf16x8*)(ksrc + j) = skv;
        }
    }
    __syncthreads();

    f32x4 sc[2][8];
    for (int mi = 0; mi < 2; mi++) for (int ni = 0; ni < 8; ni++)
        for (int e = 0; e < 4; e++) sc[mi][ni][e] = 0.f;
    #pragma unroll
    for (int ks = 0; ks < 4; ks++) {
        const int ko = ks*32 + lk;
        bf16x8 aq[2], bk[8];
        #pragma unroll
        for (int mi = 0; mi < 2; mi++)
            aq[mi] = *(const bf16x8*)&qp_sm[(w*32 + mi*16 + l15)*136 + ko];
        #pragma unroll
        for (int ni = 0; ni < 8; ni++)
            bk[ni] = *(const bf16x8*)&k_sm[(ni*16 + l15)*136 + ko];
        #pragma unroll
        for (int mi = 0; mi < 2; mi++)
            #pragma unroll
            for (int ni = 0; ni < 8; ni++)
                sc[mi][ni] = mfma16x16x32(aq[mi], bk[ni], sc[mi][ni]);
    }
    __syncthreads();

    const float scale = 0.088388347648318433f;
    #pragma unroll
    for (int mi = 0; mi < 2; mi++) {
        #pragma unroll
        for (int j = 0; j < 4; j++) {
            const int R = w*32 + mi*16 + r0 + j;
            float v[8]; float mx = -1e30f;
            #pragma unroll
            for (int ni = 0; ni < 8; ni++) {
                float x = sc[mi][ni][j] * scale;
                if (ni*16 + l15 > R) x = -1e9f;
                v[ni] = x; mx = fmaxf(mx, x);
            }
            #pragma unroll
            for (int d = 1; d < 16; d <<= 1) mx = fmaxf(mx, __shfl_xor(mx, d));
            float sum = 0.f;
            #pragma unroll
            for (int ni = 0; ni < 8; ni++) { v[ni] = __expf(v[ni] - mx); sum += v[ni]; }
            #pragma unroll
            for (int d = 1; d < 16; d <<= 1) sum += __shfl_xor(sum, d);
            const float inv = 1.f / sum;
            #pragma unroll
            for (int ni = 0; ni < 8; ni++)
                qp_sm[R*136 + ni*16 + l15] = (bf16)(v[ni] * inv);
        }
    }
    __syncthreads();

    f32x4 o[2][8];
    for (int mi = 0; mi < 2; mi++) for (int ni = 0; ni < 8; ni++)
        for (int e = 0; e < 4; e++) o[mi][ni][e] = 0.f;
    #pragma unroll
    for (int ks = 0; ks < 4; ks++) {
        const int ko = ks*32 + lk;
        bf16x8 ap[2], bv[8];
        #pragma unroll
        for (int mi = 0; mi < 2; mi++)
            ap[mi] = *(const bf16x8*)&qp_sm[(w*32 + mi*16 + l15)*136 + ko];
        #pragma unroll
        for (int ni = 0; ni < 8; ni++)
            bv[ni] = *(const bf16x8*)&vT_sm[(ni*16 + l15)*136 + ko];
        #pragma unroll
        for (int mi = 0; mi < 2; mi++)
            #pragma unroll
            for (int ni = 0; ni < 8; ni++)
                o[mi][ni] = mfma16x16x32(ap[mi], bv[ni], o[mi][ni]);
    }

    #pragma unroll
    for (int mi = 0; mi < 2; mi++)
        #pragma unroll
        for (int ni = 0; ni < 8; ni++) {
            const int R = w*32 + mi*16 + r0;
            const int c = ni*16 + l15;
            #pragma unroll
            for (int j = 0; j < 4; j++)
                lob[((size_t)(n*SEGLEN + R + j)*NBATCH + b)*DMODEL + h*DHEAD + c] =
                    (bf16)(w1 * o[mi][ni][j]);
        }

    if (tid < 128) {
        float a = 0.f;
        const bf16* row = &skT_sm[tid*136];
        #pragma unroll
        for (int ss = 0; ss < 128; ss += 8) {
            bf16x8 v8 = *(const bf16x8*)(row + ss);
            #pragma unroll
            for (int e = 0; e < 8; e++) a += (float)v8[e];
        }
        ksum[((size_t)bh*NSEG + n)*128 + tid] = a;
    }

    {
        const int wr = w >> 1, wc = w & 1;
        const size_t seg = (size_t)bh*NSEG + n;
        f32x4 ua[4][4];
        for (int mi = 0; mi < 4; mi++) for (int ni = 0; ni < 4; ni++)
            for (int e = 0; e < 4; e++) ua[mi][ni][e] = 0.f;
        #pragma unroll
        for (int ks = 0; ks < 4; ks++) {
            const int ko = ks*32 + lk;
            bf16x8 auf[4], bv[4];
            #pragma unroll
            for (int mi = 0; mi < 4; mi++)
                auf[mi] = *(const bf16x8*)&skT_sm[(wr*64 + mi*16 + l15)*136 + ko];
            #pragma unroll
            for (int ni = 0; ni < 4; ni++)
                bv[ni] = *(const bf16x8*)&vT_sm[(wc*64 + ni*16 + l15)*136 + ko];
            #pragma unroll
            for (int mi = 0; mi < 4; mi++)
                #pragma unroll
                for (int ni = 0; ni < 4; ni++)
                    ua[mi][ni] = mfma16x16x32(auf[mi], bv[ni], ua[mi][ni]);
        }
        #pragma unroll
        for (int mi = 0; mi < 4; mi++)
            #pragma unroll
            for (int ni = 0; ni < 4; ni++) {
                const int row = wr*64 + mi*16 + r0, col = wc*64 + ni*16 + l15;
                #pragma unroll
                for (int j = 0; j < 4; j++)
                    Ub[(seg << 14) + (size_t)(row + j)*128 + col] = (bf16)ua[mi][ni][j];
            }
    }
}

// ---------------------------------------------------------------------------
// scan2: mem_n = mem_{n-1} - skT@((sk@mem_{n-1})/denk) + U_n ;
//        retr  = (sq@mem_{n-1})/denq ; lob += g*retr.
// r16: qkv now holds PRE-ELU'd sq/sk (attn_local wrote in place) -> the
// per-step elu block (128 transcendental chains/thread) is GONE; fragments
// feed dots/MFMA/skT directly. Norm prefix in registers. Grid 256.
// ---------------------------------------------------------------------------
__global__ __launch_bounds__(256, 1) void scan2(const bf16* __restrict__ qkv,
                                                const bf16* __restrict__ Ub,
                                                const float* __restrict__ ksum,
                                                bf16* __restrict__ lob,
                                                const float* __restrict__ bal)
{
    __shared__ bf16 memT[16*136];
    __shared__ bf16 skT [128*136];
    __shared__ bf16 yT  [16*136];
    const int bid = blockIdx.x;
    const int bh = bid & 31, dq = bid >> 5;
    const int b = bh >> 4, h = bh & 15;
    const int tid = threadIdx.x, l = tid & 63, w = tid >> 6;
    const int l15 = l & 15, lk = (l >> 4) * 8, r0 = (l >> 4) * 4;
    const float g = 1.f / (1.f + __expf(-bal[h]));
    const size_t segb = (size_t)bh * NSEG;
    const int cdv = dq*16 + l15;

    float mast[2][4];
    #pragma unroll
    for (int mi = 0; mi < 2; mi++)
        #pragma unroll
        for (int j = 0; j < 4; j++) {
            const int row = w*32 + mi*16 + r0 + j;
            mast[mi][j] = (float)Ub[(segb << 14) + (size_t)row*128 + cdv];
            memT[l15*136 + row] = (bf16)mast[mi][j];
        }
    __syncthreads();

    float nrm[4][8];
    {
        const float* np = ksum + segb*128;
        #pragma unroll
        for (int ks = 0; ks < 4; ks++) {
            float4 a0 = *(const float4*)(np + ks*32 + lk);
            float4 a1 = *(const float4*)(np + ks*32 + lk + 4);
            nrm[ks][0]=a0.x; nrm[ks][1]=a0.y; nrm[ks][2]=a0.z; nrm[ks][3]=a0.w;
            nrm[ks][4]=a1.x; nrm[ks][5]=a1.y; nrm[ks][6]=a1.z; nrm[ks][7]=a1.w;
        }
    }

    bf16x8 qA[8], kA[8], qB[8], kB[8];

    auto loadraw = [&](int n2, bf16x8* qr, bf16x8* kr) {
        #pragma unroll
        for (int mi = 0; mi < 2; mi++)
            #pragma unroll
            for (int ks = 0; ks < 4; ks++) {
                const size_t base =
                    ((size_t)(n2*SEGLEN + w*32 + mi*16 + l15)*NBATCH + b)*QKV_N
                    + h*DHEAD + ks*32 + lk;
                qr[mi*4 + ks] = *(const bf16x8*)(qkv + base);
                kr[mi*4 + ks] = *(const bf16x8*)(qkv + base + DMODEL);
            }
    };

    auto step = [&](int n, bf16x8* curq, bf16x8* curk, bf16x8* nxtq, bf16x8* nxtk) {
        float uval[2][4], lv[2][4];
        #pragma unroll
        for (int mi = 0; mi < 2; mi++)
            #pragma unroll
            for (int j = 0; j < 4; j++) {
                const int sx = w*32 + mi*16 + r0 + j;
                uval[mi][j] = (float)Ub[((segb + n) << 14) + (size_t)sx*128 + cdv];
                lv[mi][j] = (float)lob[((size_t)(n*SEGLEN + sx)*NBATCH + b)*DMODEL
                                       + h*DHEAD + cdv];
            }
        // denominators in-register: dot(row, nrm = norm_{n-1}); sq/sk pre-elu'd
        float dqv[2][4], ivk[2][4];
        #pragma unroll
        for (int mi = 0; mi < 2; mi++) {
            float aq = 0.f, ak = 0.f;
            #pragma unroll
            for (int ks = 0; ks < 4; ks++)
                #pragma unroll
                for (int e = 0; e < 8; e++) {
                    aq += (float)curq[mi*4 + ks][e] * nrm[ks][e];
                    ak += (float)curk[mi*4 + ks][e] * nrm[ks][e];
                }
            aq += __shfl_xor(aq, 16); aq += __shfl_xor(aq, 32);
            ak += __shfl_xor(ak, 16); ak += __shfl_xor(ak, 32);
            #pragma unroll
            for (int j = 0; j < 4; j++) {
                dqv[mi][j] = __shfl(aq, r0 + j);
                ivk[mi][j] = 1.f / __shfl(ak, r0 + j);
            }
        }
        {
            const float* np = ksum + (segb + n)*128;
            #pragma unroll
            for (int ks = 0; ks < 4; ks++) {
                float4 a0 = *(const float4*)(np + ks*32 + lk);
                float4 a1 = *(const float4*)(np + ks*32 + lk + 4);
                nrm[ks][0]+=a0.x; nrm[ks][1]+=a0.y; nrm[ks][2]+=a0.z; nrm[ks][3]+=a0.w;
                nrm[ks][4]+=a1.x; nrm[ks][5]+=a1.y; nrm[ks][6]+=a1.z; nrm[ks][7]+=a1.w;
            }
        }
        #pragma unroll
        for (int mi = 0; mi < 2; mi++)
            #pragma unroll
            for (int ks = 0; ks < 4; ks++)
                #pragma unroll
                for (int e = 0; e < 8; e++)
                    skT[(ks*32 + lk + e)*136 + w*32 + mi*16 + l15] = curk[mi*4 + ks][e];
        f32x4 racc[2], yacc[2];
        #pragma unroll
        for (int mi = 0; mi < 2; mi++)
            #pragma unroll
            for (int e = 0; e < 4; e++) { racc[mi][e] = 0.f; yacc[mi][e] = 0.f; }
        #pragma unroll
        for (int ks = 0; ks < 4; ks++) {
            bf16x8 bm = *(const bf16x8*)&memT[l15*136 + ks*32 + lk];
            #pragma unroll
            for (int mi = 0; mi < 2; mi++) {
                racc[mi] = mfma16x16x32(curq[mi*4 + ks], bm, racc[mi]);
                yacc[mi] = mfma16x16x32(curk[mi*4 + ks], bm, yacc[mi]);
            }
        }
        if (n < NSEG - 1) loadraw(n + 1, nxtq, nxtk);
        #pragma unroll
        for (int mi = 0; mi < 2; mi++)
            #pragma unroll
            for (int j = 0; j < 4; j++)
                yT[l15*136 + w*32 + mi*16 + r0 + j] = (bf16)(yacc[mi][j] * ivk[mi][j]);
        __syncthreads();
        f32x4 zacc[2];
        #pragma unroll
        for (int mi = 0; mi < 2; mi++)
            #pragma unroll
            for (int e = 0; e < 4; e++) zacc[mi][e] = 0.f;
        #pragma unroll
        for (int ks = 0; ks < 4; ks++) {
            bf16x8 bz = *(const bf16x8*)&yT[l15*136 + ks*32 + lk];
            #pragma unroll
            for (int mi = 0; mi < 2; mi++) {
                bf16x8 az = *(const bf16x8*)&skT[(w*32 + mi*16 + l15)*136 + ks*32 + lk];
                zacc[mi] = mfma16x16x32(az, bz, zacc[mi]);
            }
        }
        #pragma unroll
        for (int mi = 0; mi < 2; mi++)
            #pragma unroll
            for (int j = 0; j < 4; j++) {
                const int sx = w*32 + mi*16 + r0 + j;
                const float rv = racc[mi][j] / dqv[mi][j];
                lob[((size_t)(n*SEGLEN + sx)*NBATCH + b)*DMODEL + h*DHEAD + cdv] =
                    (bf16)(lv[mi][j] + g * rv);
                mast[mi][j] += uval[mi][j] - zacc[mi][j];
                memT[l15*136 + sx] = (bf16)mast[mi][j];
            }
        __syncthreads();
    };

    loadraw(1, qA, kA);
    for (int n = 1; n < NSEG; n += 2) {
        step(n, qA, kA, qB, kB);
        if (n + 1 < NSEG) step(n + 1, qB, kB, qA, kA);
    }
}

// ---------------------------------------------------------------------------
// Workspace layout (max 295,698,432 B, proven-safe):
//   [0)            qkvb  157,286,400
//   [157,286,400)  lob    52,428,800
//   [209,715,200)  woT     8,388,608
//   [218,103,808)  abf    52,428,800   -> reused as Ub (bf16) after QKV GEMM
//   [270,532,608)  wqkvT  25,165,824   -> reused as ksum
// ---------------------------------------------------------------------------
extern "C" void kernel_launch(void* const* d_in, const int* in_sizes, int n_in,
                              void* d_out, int out_size, void* d_ws, size_t ws_size,
                              hipStream_t stream)
{
    (void)in_sizes; (void)n_in; (void)out_size; (void)ws_size;
    const float* hidden = (const float*)d_in[0];
    const float* w_qkv  = (const float*)d_in[2];
    const float* w_o    = (const float*)d_in[3];
    const float* bal    = (const float*)d_in[4];

    char* ws = (char*)d_ws;
    bf16*  qkvb  = (bf16*)ws;
    bf16*  lob   = (bf16*)(ws + 157286400);
    bf16*  woT   = (bf16*)(ws + 209715200);
    bf16*  abf   = (bf16*)(ws + 218103808);
    bf16*  Ub    = abf;
    bf16*  wqkvT = (bf16*)(ws + 270532608);
    float* ksum  = (float*)(ws + 270532608);

    dim3 blk(256);
    prep_inputs<<<18432, blk, 0, stream>>>(hidden, abf, w_qkv, wqkvT, w_o, woT);

    gemm256<true><<<dim3(MROWS/256, QKV_N/256), 512, 0, stream>>>(abf, wqkvT, qkvb, QKV_N);

    attn_local<<<dim3(NSEG*NBATCH*NHEADS), blk, 0, stream>>>(qkvb, lob, bal, ksum, Ub);
    scan2<<<256, blk, 0, stream>>>(qkvb, Ub, ksum, lob, bal);

    gemm256<false><<<dim3(MROWS/256, DMODEL/256), 512, 0, stream>>>(lob, woT, d_out, DMODEL);
}

// Round 17
// 791.346 us; speedup vs baseline: 1.1150x; 1.0504x over previous
//
#include <hip/hip_runtime.h>
#include <hip/hip_bf16.h>

typedef __bf16 bf16;
typedef __bf16 bf16x8 __attribute__((ext_vector_type(8)));
typedef __bf16 bf16x4 __attribute__((ext_vector_type(4)));
typedef float  f32x4  __attribute__((ext_vector_type(4)));

#define S_LEN   6400
#define NBATCH  2
#define DMODEL  2048
#define NHEADS  16
#define DHEAD   128
#define NSEG    50
#define SEGLEN  128
#define MROWS   (S_LEN*NBATCH)     // 12800
#define QKV_N   (3*DMODEL)         // 6144

static __device__ __forceinline__ f32x4 mfma16x16x32(bf16x8 a, bf16x8 b, f32x4 c) {
    return __builtin_amdgcn_mfma_f32_16x16x32_bf16(a, b, c, 0, 0, 0);
}
static __device__ __forceinline__ void gload_lds16(const bf16* g, bf16* l) {
    __builtin_amdgcn_global_load_lds(
        (const __attribute__((address_space(1))) void*)g,
        (__attribute__((address_space(3))) void*)l, 16, 0, 0);
}
static __device__ __forceinline__ float elu1(float x) {
    return x > 0.f ? x + 1.f : __expf(x);
}

// ---------------------------------------------------------------------------
// prep_inputs: one launch for {fp32->bf16 hidden, W_qkv^T, W_o^T}.
// ---------------------------------------------------------------------------
__global__ void prep_inputs(const float* __restrict__ hidden, bf16* __restrict__ abf,
                            const float* __restrict__ w_qkv, bf16* __restrict__ wqkvT,
                            const float* __restrict__ w_o,   bf16* __restrict__ woT)
{
    __shared__ float tile[32][33];
    const int bid = blockIdx.x;
    if (bid < 2048) {
        const int n8 = MROWS*DMODEL/8;
        const int stride = 2048 * 256;
        for (int i = bid * 256 + threadIdx.x; i < n8; i += stride) {
            const float4* p = (const float4*)(hidden + (size_t)i * 8);
            float4 v0 = p[0], v1 = p[1];
            bf16x8 o;
            o[0]=(bf16)v0.x; o[1]=(bf16)v0.y; o[2]=(bf16)v0.z; o[3]=(bf16)v0.w;
            o[4]=(bf16)v1.x; o[5]=(bf16)v1.y; o[6]=(bf16)v1.z; o[7]=(bf16)v1.w;
            *(bf16x8*)(abf + (size_t)i * 8) = o;
        }
        return;
    }
    const float* W; bf16* WT; int N, n0, k0;
    if (bid < 14336) {
        const int b2 = bid - 2048;
        W = w_qkv; WT = wqkvT; N = QKV_N;
        n0 = (b2 % 192) * 32; k0 = (b2 / 192) * 32;
    } else {
        const int b3 = bid - 14336;
        W = w_o; WT = woT; N = DMODEL;
        n0 = (b3 % 64) * 32; k0 = (b3 / 64) * 32;
    }
    const int tx = threadIdx.x & 31, ty = threadIdx.x >> 5;
    #pragma unroll
    for (int i = 0; i < 4; i++) {
        int kk = ty + i * 8;
        tile[kk][tx] = W[(size_t)(k0 + kk) * N + n0 + tx];
    }
    __syncthreads();
    #pragma unroll
    for (int i = 0; i < 4; i++) {
        int nn = ty + i * 8;
        WT[(size_t)(n0 + nn) * DMODEL + k0 + tx] = (bf16)tile[tx][nn];
    }
}

// ---------------------------------------------------------------------------
// gemm256 (r9 champion, 2D grid — XCD swizzle REFUTED r14: operands L3-fit).
// 256x256 tile, BK=32, 512 thr, phase-split read-ahead, counted vmcnt(4),
// swizzled LDS (0 conflicts). 1001 TF, MfmaUtil 45.6%.
// ---------------------------------------------------------------------------
template<bool CBF16>
__global__ __launch_bounds__(512, 2) void gemm256(const bf16* __restrict__ A,
                                                  const bf16* __restrict__ BT,
                                                  void* __restrict__ Cptr, int Ndim)
{
    constexpr int K = DMODEL;
    constexpr int NT = K / 32;
    __shared__ __align__(16) bf16 a_sm[2][256*32];
    __shared__ __align__(16) bf16 b_sm[2][256*32];

    const int tid = threadIdx.x;
    const int l = tid & 63, wid = tid >> 6;
    const int wm = wid >> 2, wn = wid & 3;
    const int brow = blockIdx.x * 256, bcol = blockIdx.y * 256;
    const int l15 = l & 15, lg = l >> 4;

    const int st_mr  = tid >> 3;
    const int st_s0  = (tid & 7) ^ (st_mr & 7);
    const int st_row = 2 * st_mr + (st_s0 >> 2);
    const int st_col = (st_s0 & 3) << 3;
    const bf16* Asrc = A  + (size_t)(brow + st_row) * K + st_col;
    const bf16* Bsrc = BT + (size_t)(bcol + st_row) * K + st_col;

    int aoff[8], boff[4];
    #pragma unroll
    for (int mi = 0; mi < 8; mi++) {
        const int r = wm*128 + mi*16 + l15, mr = r >> 1;
        aoff[mi] = mr*64 + ((((( r & 1) << 2) | lg) ^ (mr & 7)) << 3);
    }
    #pragma unroll
    for (int ni = 0; ni < 4; ni++) {
        const int r = wn*64 + ni*16 + l15, mr = r >> 1;
        boff[ni] = mr*64 + ((((( r & 1) << 2) | lg) ^ (mr & 7)) << 3);
    }

    f32x4 acc[8][4];
    #pragma unroll
    for (int mi = 0; mi < 8; mi++)
        #pragma unroll
        for (int ni = 0; ni < 4; ni++)
            #pragma unroll
            for (int e = 0; e < 4; e++) acc[mi][ni][e] = 0.f;

    auto STAGE = [&](int buf, int kt2) {
        const int k0 = kt2 * 32;
        #pragma unroll
        for (int i = 0; i < 2; i++) {
            gload_lds16(Asrc + (size_t)(i*128) * K + k0, &a_sm[buf][i*4096 + tid*8]);
            gload_lds16(Bsrc + (size_t)(i*128) * K + k0, &b_sm[buf][i*4096 + tid*8]);
        }
    };

    bf16x8 af[4], ag[4], bfr[4];
    auto READ0 = [&](int buf) {
        #pragma unroll
        for (int mi = 0; mi < 4; mi++) af[mi]  = *(const bf16x8*)&a_sm[buf][aoff[mi]];
        #pragma unroll
        for (int ni = 0; ni < 4; ni++) bfr[ni] = *(const bf16x8*)&b_sm[buf][boff[ni]];
    };
    auto READ1 = [&](int buf) {
        #pragma unroll
        for (int mi = 0; mi < 4; mi++) ag[mi] = *(const bf16x8*)&a_sm[buf][aoff[4 + mi]];
    };
    auto MFMA_LO = [&]() {
        __builtin_amdgcn_s_setprio(1);
        #pragma unroll
        for (int mi = 0; mi < 4; mi++)
            #pragma unroll
            for (int ni = 0; ni < 4; ni++)
                acc[mi][ni] = mfma16x16x32(af[mi], bfr[ni], acc[mi][ni]);
        __builtin_amdgcn_s_setprio(0);
    };
    auto MFMA_HI = [&]() {
        __builtin_amdgcn_s_setprio(1);
        #pragma unroll
        for (int mi = 0; mi < 4; mi++)
            #pragma unroll
            for (int ni = 0; ni < 4; ni++)
                acc[4 + mi][ni] = mfma16x16x32(ag[mi], bfr[ni], acc[4 + mi][ni]);
        __builtin_amdgcn_s_setprio(0);
    };

    STAGE(0, 0);
    STAGE(1, 1);
    asm volatile("s_waitcnt vmcnt(4)" ::: "memory");
    __builtin_amdgcn_sched_barrier(0);
    __builtin_amdgcn_s_barrier();
    READ0(0);

    for (int tp = 0; tp < NT - 2; tp += 2) {
        READ1(0);
        __builtin_amdgcn_sched_barrier(0);
        MFMA_LO();
        asm volatile("s_waitcnt lgkmcnt(0)" ::: "memory");
        __builtin_amdgcn_sched_barrier(0);
        __builtin_amdgcn_s_barrier();
        STAGE(0, tp + 2);
        __builtin_amdgcn_sched_barrier(0);
        MFMA_HI();
        asm volatile("s_waitcnt vmcnt(4)" ::: "memory");
        __builtin_amdgcn_sched_barrier(0);
        __builtin_amdgcn_s_barrier();

        READ0(1);
        READ1(1);
        __builtin_amdgcn_sched_barrier(0);
        MFMA_LO();
        asm volatile("s_waitcnt lgkmcnt(0)" ::: "memory");
        __builtin_amdgcn_sched_barrier(0);
        __builtin_amdgcn_s_barrier();
        STAGE(1, tp + 3);
        __builtin_amdgcn_sched_barrier(0);
        MFMA_HI();
        asm volatile("s_waitcnt vmcnt(4)" ::: "memory");
        __builtin_amdgcn_sched_barrier(0);
        __builtin_amdgcn_s_barrier();
        READ0(0);
    }

    READ1(0);
    __builtin_amdgcn_sched_barrier(0);
    MFMA_LO();
    asm volatile("s_waitcnt lgkmcnt(0)" ::: "memory");
    __builtin_amdgcn_sched_barrier(0);
    MFMA_HI();
    asm volatile("s_waitcnt vmcnt(0)" ::: "memory");
    __builtin_amdgcn_sched_barrier(0);
    __builtin_amdgcn_s_barrier();
    READ0(1);
    READ1(1);
    __builtin_amdgcn_sched_barrier(0);
    MFMA_LO();
    asm volatile("s_waitcnt lgkmcnt(0)" ::: "memory");
    __builtin_amdgcn_sched_barrier(0);
    MFMA_HI();

    #pragma unroll
    for (int mi = 0; mi < 8; mi++)
        #pragma unroll
        for (int ni = 0; ni < 4; ni++) {
            const int row = brow + wm*128 + mi*16 + lg*4;
            const int col = bcol + wn*64 + ni*16 + l15;
            #pragma unroll
            for (int j = 0; j < 4; j++) {
                float v = acc[mi][ni][j];
                if (CBF16) ((bf16*)Cptr)[(size_t)(row + j) * Ndim + col] = (bf16)v;
                else       ((float*)Cptr)[(size_t)(row + j) * Ndim + col] = v;
            }
        }
}

// ---------------------------------------------------------------------------
// attn_local (fused): lob = (1-g)*local_out; ksum[bh,n,dk] = sum_s elu1(k);
// Ub[seg] = skT @ v. Overwrites q/k in qkvb IN PLACE with elu1 values
// (r16 win: scan2's per-step elu removed; -40µs measured).
// ---------------------------------------------------------------------------
__global__ void attn_local(bf16* __restrict__ qkv,
                           bf16* __restrict__ lob,
                           const float* __restrict__ bal,
                           float* __restrict__ ksum,
                           bf16* __restrict__ Ub)
{
    __shared__ bf16 qp_sm [128*136];
    __shared__ bf16 k_sm  [128*136];
    __shared__ bf16 vT_sm [128*136];
    __shared__ bf16 skT_sm[128*136];
    const int bid = blockIdx.x;
    const int h = bid & 15, b = (bid >> 4) & 1, n = bid >> 5;
    const int bh = b*NHEADS + h;
    const int tid = threadIdx.x, l = tid & 63, w = tid >> 6;
    const int l15 = l & 15, lk = (l >> 4) * 8, r0 = (l >> 4) * 4;
    const float g  = 1.f / (1.f + __expf(-bal[h]));
    const float w1 = 1.f - g;

    {
        const int srow = tid >> 1, off = (tid & 1) << 6;
        const size_t gb = ((size_t)(n*SEGLEN + srow)*NBATCH + b)*QKV_N + h*DHEAD + off;
        bf16* qsrc = qkv + gb;
        bf16* ksrc = qkv + gb + DMODEL;
        const bf16* vsrc = qkv + gb + 2*DMODEL;
        #pragma unroll
        for (int j = 0; j < 64; j += 8) {
            bf16x8 qv = *(const bf16x8*)(qsrc + j);
            bf16x8 kv = *(const bf16x8*)(ksrc + j);
            bf16x8 vv = *(const bf16x8*)(vsrc + j);
            bf16x8 sqv, skv;
            #pragma unroll
            for (int e = 0; e < 8; e++) {
                sqv[e] = (bf16)elu1((float)qv[e]);
                skv[e] = (bf16)elu1((float)kv[e]);
            }
            *(bf16x8*)&qp_sm[srow*136 + off + j] = qv;
            *(bf16x8*)&k_sm [srow*136 + off + j] = kv;
            #pragma unroll
            for (int e = 0; e < 8; e++) {
                vT_sm [(off + j + e)*136 + srow] = vv[e];
                skT_sm[(off + j + e)*136 + srow] = skv[e];
            }
            *(bf16x8*)(qsrc + j) = sqv;   // in-place elu for scan2
            *(bf16x8*)(ksrc + j) = skv;
        }
    }
    __syncthreads();

    f32x4 sc[2][8];
    for (int mi = 0; mi < 2; mi++) for (int ni = 0; ni < 8; ni++)
        for (int e = 0; e < 4; e++) sc[mi][ni][e] = 0.f;
    #pragma unroll
    for (int ks = 0; ks < 4; ks++) {
        const int ko = ks*32 + lk;
        bf16x8 aq[2], bk[8];
        #pragma unroll
        for (int mi = 0; mi < 2; mi++)
            aq[mi] = *(const bf16x8*)&qp_sm[(w*32 + mi*16 + l15)*136 + ko];
        #pragma unroll
        for (int ni = 0; ni < 8; ni++)
            bk[ni] = *(const bf16x8*)&k_sm[(ni*16 + l15)*136 + ko];
        #pragma unroll
        for (int mi = 0; mi < 2; mi++)
            #pragma unroll
            for (int ni = 0; ni < 8; ni++)
                sc[mi][ni] = mfma16x16x32(aq[mi], bk[ni], sc[mi][ni]);
    }
    __syncthreads();

    const float scale = 0.088388347648318433f;
    #pragma unroll
    for (int mi = 0; mi < 2; mi++) {
        #pragma unroll
        for (int j = 0; j < 4; j++) {
            const int R = w*32 + mi*16 + r0 + j;
            float v[8]; float mx = -1e30f;
            #pragma unroll
            for (int ni = 0; ni < 8; ni++) {
                float x = sc[mi][ni][j] * scale;
                if (ni*16 + l15 > R) x = -1e9f;
                v[ni] = x; mx = fmaxf(mx, x);
            }
            #pragma unroll
            for (int d = 1; d < 16; d <<= 1) mx = fmaxf(mx, __shfl_xor(mx, d));
            float sum = 0.f;
            #pragma unroll
            for (int ni = 0; ni < 8; ni++) { v[ni] = __expf(v[ni] - mx); sum += v[ni]; }
            #pragma unroll
            for (int d = 1; d < 16; d <<= 1) sum += __shfl_xor(sum, d);
            const float inv = 1.f / sum;
            #pragma unroll
            for (int ni = 0; ni < 8; ni++)
                qp_sm[R*136 + ni*16 + l15] = (bf16)(v[ni] * inv);
        }
    }
    __syncthreads();

    f32x4 o[2][8];
    for (int mi = 0; mi < 2; mi++) for (int ni = 0; ni < 8; ni++)
        for (int e = 0; e < 4; e++) o[mi][ni][e] = 0.f;
    #pragma unroll
    for (int ks = 0; ks < 4; ks++) {
        const int ko = ks*32 + lk;
        bf16x8 ap[2], bv[8];
        #pragma unroll
        for (int mi = 0; mi < 2; mi++)
            ap[mi] = *(const bf16x8*)&qp_sm[(w*32 + mi*16 + l15)*136 + ko];
        #pragma unroll
        for (int ni = 0; ni < 8; ni++)
            bv[ni] = *(const bf16x8*)&vT_sm[(ni*16 + l15)*136 + ko];
        #pragma unroll
        for (int mi = 0; mi < 2; mi++)
            #pragma unroll
            for (int ni = 0; ni < 8; ni++)
                o[mi][ni] = mfma16x16x32(ap[mi], bv[ni], o[mi][ni]);
    }

    #pragma unroll
    for (int mi = 0; mi < 2; mi++)
        #pragma unroll
        for (int ni = 0; ni < 8; ni++) {
            const int R = w*32 + mi*16 + r0;
            const int c = ni*16 + l15;
            #pragma unroll
            for (int j = 0; j < 4; j++)
                lob[((size_t)(n*SEGLEN + R + j)*NBATCH + b)*DMODEL + h*DHEAD + c] =
                    (bf16)(w1 * o[mi][ni][j]);
        }

    if (tid < 128) {
        float a = 0.f;
        const bf16* row = &skT_sm[tid*136];
        #pragma unroll
        for (int ss = 0; ss < 128; ss += 8) {
            bf16x8 v8 = *(const bf16x8*)(row + ss);
            #pragma unroll
            for (int e = 0; e < 8; e++) a += (float)v8[e];
        }
        ksum[((size_t)bh*NSEG + n)*128 + tid] = a;
    }

    {
        const int wr = w >> 1, wc = w & 1;
        const size_t seg = (size_t)bh*NSEG + n;
        f32x4 ua[4][4];
        for (int mi = 0; mi < 4; mi++) for (int ni = 0; ni < 4; ni++)
            for (int e = 0; e < 4; e++) ua[mi][ni][e] = 0.f;
        #pragma unroll
        for (int ks = 0; ks < 4; ks++) {
            const int ko = ks*32 + lk;
            bf16x8 auf[4], bv[4];
            #pragma unroll
            for (int mi = 0; mi < 4; mi++)
                auf[mi] = *(const bf16x8*)&skT_sm[(wr*64 + mi*16 + l15)*136 + ko];
            #pragma unroll
            for (int ni = 0; ni < 4; ni++)
                bv[ni] = *(const bf16x8*)&vT_sm[(wc*64 + ni*16 + l15)*136 + ko];
            #pragma unroll
            for (int mi = 0; mi < 4; mi++)
                #pragma unroll
                for (int ni = 0; ni < 4; ni++)
                    ua[mi][ni] = mfma16x16x32(auf[mi], bv[ni], ua[mi][ni]);
        }
        #pragma unroll
        for (int mi = 0; mi < 4; mi++)
            #pragma unroll
            for (int ni = 0; ni < 4; ni++) {
                const int row = wr*64 + mi*16 + r0, col = wc*64 + ni*16 + l15;
                #pragma unroll
                for (int j = 0; j < 4; j++)
                    Ub[(seg << 14) + (size_t)(row + j)*128 + col] = (bf16)ua[mi][ni][j];
            }
    }
}

// ---------------------------------------------------------------------------
// scan2 (r17): 512 threads = 8 WAVES, wave w owns 16 s/dk rows (was 4 waves
// x 32 rows at 1 wave/SIMD). Per-thread work halves; 2 waves/SIMD co-resident
// -> serial-chain latency hidden. Math/order identical to r16 (bit-identical
// output). qkv holds pre-elu'd sq/sk. Norm prefix in registers. Grid 256.
// ---------------------------------------------------------------------------
__global__ __launch_bounds__(512, 1) void scan2(const bf16* __restrict__ qkv,
                                                const bf16* __restrict__ Ub,
                                                const float* __restrict__ ksum,
                                                bf16* __restrict__ lob,
                                                const float* __restrict__ bal)
{
    __shared__ bf16 memT[16*136];
    __shared__ bf16 skT [128*136];
    __shared__ bf16 yT  [16*136];
    const int bid = blockIdx.x;
    const int bh = bid & 31, dq = bid >> 5;
    const int b = bh >> 4, h = bh & 15;
    const int tid = threadIdx.x, l = tid & 63, w = tid >> 6;   // w 0..7
    const int l15 = l & 15, lk = (l >> 4) * 8, r0 = (l >> 4) * 4;
    const int srow = w * 16;                                    // wave's row base
    const float g = 1.f / (1.f + __expf(-bal[h]));
    const size_t segb = (size_t)bh * NSEG;
    const int cdv = dq*16 + l15;

    float mast[4];
    #pragma unroll
    for (int j = 0; j < 4; j++) {
        const int row = srow + r0 + j;
        mast[j] = (float)Ub[(segb << 14) + (size_t)row*128 + cdv];
        memT[l15*136 + row] = (bf16)mast[j];
    }
    __syncthreads();

    float nrm[4][8];
    {
        const float* np = ksum + segb*128;
        #pragma unroll
        for (int ks = 0; ks < 4; ks++) {
            float4 a0 = *(const float4*)(np + ks*32 + lk);
            float4 a1 = *(const float4*)(np + ks*32 + lk + 4);
            nrm[ks][0]=a0.x; nrm[ks][1]=a0.y; nrm[ks][2]=a0.z; nrm[ks][3]=a0.w;
            nrm[ks][4]=a1.x; nrm[ks][5]=a1.y; nrm[ks][6]=a1.z; nrm[ks][7]=a1.w;
        }
    }

    bf16x8 qA[4], kA[4], qB[4], kB[4];

    auto loadraw = [&](int n2, bf16x8* qr, bf16x8* kr) {
        #pragma unroll
        for (int ks = 0; ks < 4; ks++) {
            const size_t base =
                ((size_t)(n2*SEGLEN + srow + l15)*NBATCH + b)*QKV_N
                + h*DHEAD + ks*32 + lk;
            qr[ks] = *(const bf16x8*)(qkv + base);
            kr[ks] = *(const bf16x8*)(qkv + base + DMODEL);
        }
    };

    auto step = [&](int n, bf16x8* curq, bf16x8* curk, bf16x8* nxtq, bf16x8* nxtk) {
        float uval[4], lv[4];
        #pragma unroll
        for (int j = 0; j < 4; j++) {
            const int sx = srow + r0 + j;
            uval[j] = (float)Ub[((segb + n) << 14) + (size_t)sx*128 + cdv];
            lv[j] = (float)lob[((size_t)(n*SEGLEN + sx)*NBATCH + b)*DMODEL
                               + h*DHEAD + cdv];
        }
        // denominators: dot(row, nrm = norm_{n-1}); sq/sk pre-elu'd
        float dqv[4], ivk[4];
        {
            float aq = 0.f, ak = 0.f;
            #pragma unroll
            for (int ks = 0; ks < 4; ks++)
                #pragma unroll
                for (int e = 0; e < 8; e++) {
                    aq += (float)curq[ks][e] * nrm[ks][e];
                    ak += (float)curk[ks][e] * nrm[ks][e];
                }
            aq += __shfl_xor(aq, 16); aq += __shfl_xor(aq, 32);
            ak += __shfl_xor(ak, 16); ak += __shfl_xor(ak, 32);
            #pragma unroll
            for (int j = 0; j < 4; j++) {
                dqv[j] = __shfl(aq, r0 + j);
                ivk[j] = 1.f / __shfl(ak, r0 + j);
            }
        }
        {
            const float* np = ksum + (segb + n)*128;
            #pragma unroll
            for (int ks = 0; ks < 4; ks++) {
                float4 a0 = *(const float4*)(np + ks*32 + lk);
                float4 a1 = *(const float4*)(np + ks*32 + lk + 4);
                nrm[ks][0]+=a0.x; nrm[ks][1]+=a0.y; nrm[ks][2]+=a0.z; nrm[ks][3]+=a0.w;
                nrm[ks][4]+=a1.x; nrm[ks][5]+=a1.y; nrm[ks][6]+=a1.z; nrm[ks][7]+=a1.w;
            }
        }
        // skT[dk][s] transposed write (wave's 16 s-rows)
        #pragma unroll
        for (int ks = 0; ks < 4; ks++)
            #pragma unroll
            for (int e = 0; e < 8; e++)
                skT[(ks*32 + lk + e)*136 + srow + l15] = curk[ks][e];
        f32x4 racc, yacc;
        #pragma unroll
        for (int e = 0; e < 4; e++) { racc[e] = 0.f; yacc[e] = 0.f; }
        #pragma unroll
        for (int ks = 0; ks < 4; ks++) {
            bf16x8 bm = *(const bf16x8*)&memT[l15*136 + ks*32 + lk];
            racc = mfma16x16x32(curq[ks], bm, racc);
            yacc = mfma16x16x32(curk[ks], bm, yacc);
        }
        if (n < NSEG - 1) loadraw(n + 1, nxtq, nxtk);
        #pragma unroll
        for (int j = 0; j < 4; j++)
            yT[l15*136 + srow + r0 + j] = (bf16)(yacc[j] * ivk[j]);
        __syncthreads();
        f32x4 zacc;
        #pragma unroll
        for (int e = 0; e < 4; e++) zacc[e] = 0.f;
        #pragma unroll
        for (int ks = 0; ks < 4; ks++) {
            bf16x8 bz = *(const bf16x8*)&yT[l15*136 + ks*32 + lk];
            bf16x8 az = *(const bf16x8*)&skT[(srow + l15)*136 + ks*32 + lk];
            zacc = mfma16x16x32(az, bz, zacc);
        }
        #pragma unroll
        for (int j = 0; j < 4; j++) {
            const int sx = srow + r0 + j;
            const float rv = racc[j] / dqv[j];
            lob[((size_t)(n*SEGLEN + sx)*NBATCH + b)*DMODEL + h*DHEAD + cdv] =
                (bf16)(lv[j] + g * rv);
            mast[j] += uval[j] - zacc[j];
            memT[l15*136 + sx] = (bf16)mast[j];
        }
        __syncthreads();
    };

    loadraw(1, qA, kA);
    for (int n = 1; n < NSEG; n += 2) {
        step(n, qA, kA, qB, kB);
        if (n + 1 < NSEG) step(n + 1, qB, kB, qA, kA);
    }
}

// ---------------------------------------------------------------------------
// Workspace layout (max 295,698,432 B, proven-safe):
//   [0)            qkvb  157,286,400
//   [157,286,400)  lob    52,428,800
//   [209,715,200)  woT     8,388,608
//   [218,103,808)  abf    52,428,800   -> reused as Ub (bf16) after QKV GEMM
//   [270,532,608)  wqkvT  25,165,824   -> reused as ksum
// ---------------------------------------------------------------------------
extern "C" void kernel_launch(void* const* d_in, const int* in_sizes, int n_in,
                              void* d_out, int out_size, void* d_ws, size_t ws_size,
                              hipStream_t stream)
{
    (void)in_sizes; (void)n_in; (void)out_size; (void)ws_size;
    const float* hidden = (const float*)d_in[0];
    const float* w_qkv  = (const float*)d_in[2];
    const float* w_o    = (const float*)d_in[3];
    const float* bal    = (const float*)d_in[4];

    char* ws = (char*)d_ws;
    bf16*  qkvb  = (bf16*)ws;
    bf16*  lob   = (bf16*)(ws + 157286400);
    bf16*  woT   = (bf16*)(ws + 209715200);
    bf16*  abf   = (bf16*)(ws + 218103808);
    bf16*  Ub    = abf;
    bf16*  wqkvT = (bf16*)(ws + 270532608);
    float* ksum  = (float*)(ws + 270532608);

    dim3 blk(256);
    prep_inputs<<<18432, blk, 0, stream>>>(hidden, abf, w_qkv, wqkvT, w_o, woT);

    gemm256<true><<<dim3(MROWS/256, QKV_N/256), 512, 0, stream>>>(abf, wqkvT, qkvb, QKV_N);

    attn_local<<<dim3(NSEG*NBATCH*NHEADS), blk, 0, stream>>>(qkvb, lob, bal, ksum, Ub);
    scan2<<<256, 512, 0, stream>>>(qkvb, Ub, ksum, lob, bal);

    gemm256<false><<<dim3(MROWS/256, DMODEL/256), 512, 0, stream>>>(lob, woT, d_out, DMODEL);
}

// Round 18
// 751.042 us; speedup vs baseline: 1.1748x; 1.0537x over previous
//
#include <hip/hip_runtime.h>
#include <hip/hip_bf16.h>

typedef __bf16 bf16;
typedef __bf16 bf16x8 __attribute__((ext_vector_type(8)));
typedef __bf16 bf16x4 __attribute__((ext_vector_type(4)));
typedef float  f32x4  __attribute__((ext_vector_type(4)));

#define S_LEN   6400
#define NBATCH  2
#define DMODEL  2048
#define NHEADS  16
#define DHEAD   128
#define NSEG    50
#define SEGLEN  128
#define MROWS   (S_LEN*NBATCH)     // 12800
#define QKV_N   (3*DMODEL)         // 6144

static __device__ __forceinline__ f32x4 mfma16x16x32(bf16x8 a, bf16x8 b, f32x4 c) {
    return __builtin_amdgcn_mfma_f32_16x16x32_bf16(a, b, c, 0, 0, 0);
}
static __device__ __forceinline__ void gload_lds16(const bf16* g, bf16* l) {
    __builtin_amdgcn_global_load_lds(
        (const __attribute__((address_space(1))) void*)g,
        (__attribute__((address_space(3))) void*)l, 16, 0, 0);
}
static __device__ __forceinline__ float elu1(float x) {
    return x > 0.f ? x + 1.f : __expf(x);
}

// ---------------------------------------------------------------------------
// prep_inputs: one launch for {fp32->bf16 hidden, W_qkv^T, W_o^T}.
// ---------------------------------------------------------------------------
__global__ void prep_inputs(const float* __restrict__ hidden, bf16* __restrict__ abf,
                            const float* __restrict__ w_qkv, bf16* __restrict__ wqkvT,
                            const float* __restrict__ w_o,   bf16* __restrict__ woT)
{
    __shared__ float tile[32][33];
    const int bid = blockIdx.x;
    if (bid < 2048) {
        const int n8 = MROWS*DMODEL/8;
        const int stride = 2048 * 256;
        for (int i = bid * 256 + threadIdx.x; i < n8; i += stride) {
            const float4* p = (const float4*)(hidden + (size_t)i * 8);
            float4 v0 = p[0], v1 = p[1];
            bf16x8 o;
            o[0]=(bf16)v0.x; o[1]=(bf16)v0.y; o[2]=(bf16)v0.z; o[3]=(bf16)v0.w;
            o[4]=(bf16)v1.x; o[5]=(bf16)v1.y; o[6]=(bf16)v1.z; o[7]=(bf16)v1.w;
            *(bf16x8*)(abf + (size_t)i * 8) = o;
        }
        return;
    }
    const float* W; bf16* WT; int N, n0, k0;
    if (bid < 14336) {
        const int b2 = bid - 2048;
        W = w_qkv; WT = wqkvT; N = QKV_N;
        n0 = (b2 % 192) * 32; k0 = (b2 / 192) * 32;
    } else {
        const int b3 = bid - 14336;
        W = w_o; WT = woT; N = DMODEL;
        n0 = (b3 % 64) * 32; k0 = (b3 / 64) * 32;
    }
    const int tx = threadIdx.x & 31, ty = threadIdx.x >> 5;
    #pragma unroll
    for (int i = 0; i < 4; i++) {
        int kk = ty + i * 8;
        tile[kk][tx] = W[(size_t)(k0 + kk) * N + n0 + tx];
    }
    __syncthreads();
    #pragma unroll
    for (int i = 0; i < 4; i++) {
        int nn = ty + i * 8;
        WT[(size_t)(n0 + nn) * DMODEL + k0 + tx] = (bf16)tile[tx][nn];
    }
}

// ---------------------------------------------------------------------------
// gemm256 (r9 champion, 2D grid — XCD swizzle REFUTED r14: operands L3-fit).
// 256x256 tile, BK=32, 512 thr, phase-split read-ahead, counted vmcnt(4),
// swizzled LDS (0 conflicts). 1001 TF, MfmaUtil 45.6%.
// ---------------------------------------------------------------------------
template<bool CBF16>
__global__ __launch_bounds__(512, 2) void gemm256(const bf16* __restrict__ A,
                                                  const bf16* __restrict__ BT,
                                                  void* __restrict__ Cptr, int Ndim)
{
    constexpr int K = DMODEL;
    constexpr int NT = K / 32;
    __shared__ __align__(16) bf16 a_sm[2][256*32];
    __shared__ __align__(16) bf16 b_sm[2][256*32];

    const int tid = threadIdx.x;
    const int l = tid & 63, wid = tid >> 6;
    const int wm = wid >> 2, wn = wid & 3;
    const int brow = blockIdx.x * 256, bcol = blockIdx.y * 256;
    const int l15 = l & 15, lg = l >> 4;

    const int st_mr  = tid >> 3;
    const int st_s0  = (tid & 7) ^ (st_mr & 7);
    const int st_row = 2 * st_mr + (st_s0 >> 2);
    const int st_col = (st_s0 & 3) << 3;
    const bf16* Asrc = A  + (size_t)(brow + st_row) * K + st_col;
    const bf16* Bsrc = BT + (size_t)(bcol + st_row) * K + st_col;

    int aoff[8], boff[4];
    #pragma unroll
    for (int mi = 0; mi < 8; mi++) {
        const int r = wm*128 + mi*16 + l15, mr = r >> 1;
        aoff[mi] = mr*64 + ((((( r & 1) << 2) | lg) ^ (mr & 7)) << 3);
    }
    #pragma unroll
    for (int ni = 0; ni < 4; ni++) {
        const int r = wn*64 + ni*16 + l15, mr = r >> 1;
        boff[ni] = mr*64 + ((((( r & 1) << 2) | lg) ^ (mr & 7)) << 3);
    }

    f32x4 acc[8][4];
    #pragma unroll
    for (int mi = 0; mi < 8; mi++)
        #pragma unroll
        for (int ni = 0; ni < 4; ni++)
            #pragma unroll
            for (int e = 0; e < 4; e++) acc[mi][ni][e] = 0.f;

    auto STAGE = [&](int buf, int kt2) {
        const int k0 = kt2 * 32;
        #pragma unroll
        for (int i = 0; i < 2; i++) {
            gload_lds16(Asrc + (size_t)(i*128) * K + k0, &a_sm[buf][i*4096 + tid*8]);
            gload_lds16(Bsrc + (size_t)(i*128) * K + k0, &b_sm[buf][i*4096 + tid*8]);
        }
    };

    bf16x8 af[4], ag[4], bfr[4];
    auto READ0 = [&](int buf) {
        #pragma unroll
        for (int mi = 0; mi < 4; mi++) af[mi]  = *(const bf16x8*)&a_sm[buf][aoff[mi]];
        #pragma unroll
        for (int ni = 0; ni < 4; ni++) bfr[ni] = *(const bf16x8*)&b_sm[buf][boff[ni]];
    };
    auto READ1 = [&](int buf) {
        #pragma unroll
        for (int mi = 0; mi < 4; mi++) ag[mi] = *(const bf16x8*)&a_sm[buf][aoff[4 + mi]];
    };
    auto MFMA_LO = [&]() {
        __builtin_amdgcn_s_setprio(1);
        #pragma unroll
        for (int mi = 0; mi < 4; mi++)
            #pragma unroll
            for (int ni = 0; ni < 4; ni++)
                acc[mi][ni] = mfma16x16x32(af[mi], bfr[ni], acc[mi][ni]);
        __builtin_amdgcn_s_setprio(0);
    };
    auto MFMA_HI = [&]() {
        __builtin_amdgcn_s_setprio(1);
        #pragma unroll
        for (int mi = 0; mi < 4; mi++)
            #pragma unroll
            for (int ni = 0; ni < 4; ni++)
                acc[4 + mi][ni] = mfma16x16x32(ag[mi], bfr[ni], acc[4 + mi][ni]);
        __builtin_amdgcn_s_setprio(0);
    };

    STAGE(0, 0);
    STAGE(1, 1);
    asm volatile("s_waitcnt vmcnt(4)" ::: "memory");
    __builtin_amdgcn_sched_barrier(0);
    __builtin_amdgcn_s_barrier();
    READ0(0);

    for (int tp = 0; tp < NT - 2; tp += 2) {
        READ1(0);
        __builtin_amdgcn_sched_barrier(0);
        MFMA_LO();
        asm volatile("s_waitcnt lgkmcnt(0)" ::: "memory");
        __builtin_amdgcn_sched_barrier(0);
        __builtin_amdgcn_s_barrier();
        STAGE(0, tp + 2);
        __builtin_amdgcn_sched_barrier(0);
        MFMA_HI();
        asm volatile("s_waitcnt vmcnt(4)" ::: "memory");
        __builtin_amdgcn_sched_barrier(0);
        __builtin_amdgcn_s_barrier();

        READ0(1);
        READ1(1);
        __builtin_amdgcn_sched_barrier(0);
        MFMA_LO();
        asm volatile("s_waitcnt lgkmcnt(0)" ::: "memory");
        __builtin_amdgcn_sched_barrier(0);
        __builtin_amdgcn_s_barrier();
        STAGE(1, tp + 3);
        __builtin_amdgcn_sched_barrier(0);
        MFMA_HI();
        asm volatile("s_waitcnt vmcnt(4)" ::: "memory");
        __builtin_amdgcn_sched_barrier(0);
        __builtin_amdgcn_s_barrier();
        READ0(0);
    }

    READ1(0);
    __builtin_amdgcn_sched_barrier(0);
    MFMA_LO();
    asm volatile("s_waitcnt lgkmcnt(0)" ::: "memory");
    __builtin_amdgcn_sched_barrier(0);
    MFMA_HI();
    asm volatile("s_waitcnt vmcnt(0)" ::: "memory");
    __builtin_amdgcn_sched_barrier(0);
    __builtin_amdgcn_s_barrier();
    READ0(1);
    READ1(1);
    __builtin_amdgcn_sched_barrier(0);
    MFMA_LO();
    asm volatile("s_waitcnt lgkmcnt(0)" ::: "memory");
    __builtin_amdgcn_sched_barrier(0);
    MFMA_HI();

    #pragma unroll
    for (int mi = 0; mi < 8; mi++)
        #pragma unroll
        for (int ni = 0; ni < 4; ni++) {
            const int row = brow + wm*128 + mi*16 + lg*4;
            const int col = bcol + wn*64 + ni*16 + l15;
            #pragma unroll
            for (int j = 0; j < 4; j++) {
                float v = acc[mi][ni][j];
                if (CBF16) ((bf16*)Cptr)[(size_t)(row + j) * Ndim + col] = (bf16)v;
                else       ((float*)Cptr)[(size_t)(row + j) * Ndim + col] = v;
            }
        }
}

// ---------------------------------------------------------------------------
// attn_local (r18): 512 threads = 8 WAVES (was 4 at 1 wave/SIMD) -> 2
// waves/SIMD co-resident. Wave w owns 16 q-rows (QK^T/softmax/PV/lob);
// U uses 2x4 wave grid. Same math/rounding as r17 (bit-identical).
// Also: lob=(1-g)*local; ksum; Ub=skT@v; in-place elu of q/k in qkvb.
// ---------------------------------------------------------------------------
__global__ __launch_bounds__(512, 1) void attn_local(bf16* __restrict__ qkv,
                                                     bf16* __restrict__ lob,
                                                     const float* __restrict__ bal,
                                                     float* __restrict__ ksum,
                                                     bf16* __restrict__ Ub)
{
    __shared__ bf16 qp_sm [128*136];
    __shared__ bf16 k_sm  [128*136];
    __shared__ bf16 vT_sm [128*136];
    __shared__ bf16 skT_sm[128*136];
    const int bid = blockIdx.x;
    const int h = bid & 15, b = (bid >> 4) & 1, n = bid >> 5;
    const int bh = b*NHEADS + h;
    const int tid = threadIdx.x, l = tid & 63, w = tid >> 6;   // w 0..7
    const int l15 = l & 15, lk = (l >> 4) * 8, r0 = (l >> 4) * 4;
    const float g  = 1.f / (1.f + __expf(-bal[h]));
    const float w1 = 1.f - g;

    {   // stage: 32 elems/thread (512 thr x 32 = 128x128)
        const int srow = tid >> 2, off = (tid & 3) << 5;
        const size_t gb = ((size_t)(n*SEGLEN + srow)*NBATCH + b)*QKV_N + h*DHEAD + off;
        bf16* qsrc = qkv + gb;
        bf16* ksrc = qkv + gb + DMODEL;
        const bf16* vsrc = qkv + gb + 2*DMODEL;
        #pragma unroll
        for (int j = 0; j < 32; j += 8) {
            bf16x8 qv = *(const bf16x8*)(qsrc + j);
            bf16x8 kv = *(const bf16x8*)(ksrc + j);
            bf16x8 vv = *(const bf16x8*)(vsrc + j);
            bf16x8 sqv, skv;
            #pragma unroll
            for (int e = 0; e < 8; e++) {
                sqv[e] = (bf16)elu1((float)qv[e]);
                skv[e] = (bf16)elu1((float)kv[e]);
            }
            *(bf16x8*)&qp_sm[srow*136 + off + j] = qv;
            *(bf16x8*)&k_sm [srow*136 + off + j] = kv;
            #pragma unroll
            for (int e = 0; e < 8; e++) {
                vT_sm [(off + j + e)*136 + srow] = vv[e];
                skT_sm[(off + j + e)*136 + srow] = skv[e];
            }
            *(bf16x8*)(qsrc + j) = sqv;   // in-place elu for scan2
            *(bf16x8*)(ksrc + j) = skv;
        }
    }
    __syncthreads();

    // ---- S = q @ k^T : wave w owns q-rows w*16..w*16+15
    f32x4 sc[8];
    #pragma unroll
    for (int ni = 0; ni < 8; ni++)
        #pragma unroll
        for (int e = 0; e < 4; e++) sc[ni][e] = 0.f;
    #pragma unroll
    for (int ks = 0; ks < 4; ks++) {
        const int ko = ks*32 + lk;
        bf16x8 aq = *(const bf16x8*)&qp_sm[(w*16 + l15)*136 + ko];
        bf16x8 bk[8];
        #pragma unroll
        for (int ni = 0; ni < 8; ni++)
            bk[ni] = *(const bf16x8*)&k_sm[(ni*16 + l15)*136 + ko];
        #pragma unroll
        for (int ni = 0; ni < 8; ni++)
            sc[ni] = mfma16x16x32(aq, bk[ni], sc[ni]);
    }
    __syncthreads();

    // ---- causal mask + row softmax, P -> qp_sm (own 16 rows)
    const float scale = 0.088388347648318433f;
    #pragma unroll
    for (int j = 0; j < 4; j++) {
        const int R = w*16 + r0 + j;
        float v[8]; float mx = -1e30f;
        #pragma unroll
        for (int ni = 0; ni < 8; ni++) {
            float x = sc[ni][j] * scale;
            if (ni*16 + l15 > R) x = -1e9f;
            v[ni] = x; mx = fmaxf(mx, x);
        }
        #pragma unroll
        for (int d = 1; d < 16; d <<= 1) mx = fmaxf(mx, __shfl_xor(mx, d));
        float sum = 0.f;
        #pragma unroll
        for (int ni = 0; ni < 8; ni++) { v[ni] = __expf(v[ni] - mx); sum += v[ni]; }
        #pragma unroll
        for (int d = 1; d < 16; d <<= 1) sum += __shfl_xor(sum, d);
        const float inv = 1.f / sum;
        #pragma unroll
        for (int ni = 0; ni < 8; ni++)
            qp_sm[R*136 + ni*16 + l15] = (bf16)(v[ni] * inv);
    }
    __syncthreads();

    // ---- O = P @ V
    f32x4 o[8];
    #pragma unroll
    for (int ni = 0; ni < 8; ni++)
        #pragma unroll
        for (int e = 0; e < 4; e++) o[ni][e] = 0.f;
    #pragma unroll
    for (int ks = 0; ks < 4; ks++) {
        const int ko = ks*32 + lk;
        bf16x8 ap = *(const bf16x8*)&qp_sm[(w*16 + l15)*136 + ko];
        bf16x8 bv[8];
        #pragma unroll
        for (int ni = 0; ni < 8; ni++)
            bv[ni] = *(const bf16x8*)&vT_sm[(ni*16 + l15)*136 + ko];
        #pragma unroll
        for (int ni = 0; ni < 8; ni++)
            o[ni] = mfma16x16x32(ap, bv[ni], o[ni]);
    }

    #pragma unroll
    for (int ni = 0; ni < 8; ni++) {
        const int R = w*16 + r0;
        const int c = ni*16 + l15;
        #pragma unroll
        for (int j = 0; j < 4; j++)
            lob[((size_t)(n*SEGLEN + R + j)*NBATCH + b)*DMODEL + h*DHEAD + c] =
                (bf16)(w1 * o[ni][j]);
    }

    // ---- ksum (elu'd k already in skT rows)
    if (tid < 128) {
        float a = 0.f;
        const bf16* row = &skT_sm[tid*136];
        #pragma unroll
        for (int ss = 0; ss < 128; ss += 8) {
            bf16x8 v8 = *(const bf16x8*)(row + ss);
            #pragma unroll
            for (int e = 0; e < 8; e++) a += (float)v8[e];
        }
        ksum[((size_t)bh*NSEG + n)*128 + tid] = a;
    }

    // ---- U = skT @ v : 8-wave grid 2(rows of 64) x 4(cols of 32)
    {
        const int wr = w >> 2, wc = w & 3;
        const size_t seg = (size_t)bh*NSEG + n;
        f32x4 ua[4][2];
        #pragma unroll
        for (int mi = 0; mi < 4; mi++)
            #pragma unroll
            for (int ni = 0; ni < 2; ni++)
                #pragma unroll
                for (int e = 0; e < 4; e++) ua[mi][ni][e] = 0.f;
        #pragma unroll
        for (int ks = 0; ks < 4; ks++) {
            const int ko = ks*32 + lk;
            bf16x8 auf[4], bv2[2];
            #pragma unroll
            for (int mi = 0; mi < 4; mi++)
                auf[mi] = *(const bf16x8*)&skT_sm[(wr*64 + mi*16 + l15)*136 + ko];
            #pragma unroll
            for (int ni = 0; ni < 2; ni++)
                bv2[ni] = *(const bf16x8*)&vT_sm[(wc*32 + ni*16 + l15)*136 + ko];
            #pragma unroll
            for (int mi = 0; mi < 4; mi++)
                #pragma unroll
                for (int ni = 0; ni < 2; ni++)
                    ua[mi][ni] = mfma16x16x32(auf[mi], bv2[ni], ua[mi][ni]);
        }
        #pragma unroll
        for (int mi = 0; mi < 4; mi++)
            #pragma unroll
            for (int ni = 0; ni < 2; ni++) {
                const int row = wr*64 + mi*16 + r0, col = wc*32 + ni*16 + l15;
                #pragma unroll
                for (int j = 0; j < 4; j++)
                    Ub[(seg << 14) + (size_t)(row + j)*128 + col] = (bf16)ua[mi][ni][j];
            }
    }
}

// ---------------------------------------------------------------------------
// scan2 (r17 proven): 512 thr = 8 waves, wave owns 16 s/dk rows; 2 waves/SIMD.
// qkv holds pre-elu'd sq/sk. Norm prefix in registers. Grid 256.
// ---------------------------------------------------------------------------
__global__ __launch_bounds__(512, 1) void scan2(const bf16* __restrict__ qkv,
                                                const bf16* __restrict__ Ub,
                                                const float* __restrict__ ksum,
                                                bf16* __restrict__ lob,
                                                const float* __restrict__ bal)
{
    __shared__ bf16 memT[16*136];
    __shared__ bf16 skT [128*136];
    __shared__ bf16 yT  [16*136];
    const int bid = blockIdx.x;
    const int bh = bid & 31, dq = bid >> 5;
    const int b = bh >> 4, h = bh & 15;
    const int tid = threadIdx.x, l = tid & 63, w = tid >> 6;   // w 0..7
    const int l15 = l & 15, lk = (l >> 4) * 8, r0 = (l >> 4) * 4;
    const int srow = w * 16;
    const float g = 1.f / (1.f + __expf(-bal[h]));
    const size_t segb = (size_t)bh * NSEG;
    const int cdv = dq*16 + l15;

    float mast[4];
    #pragma unroll
    for (int j = 0; j < 4; j++) {
        const int row = srow + r0 + j;
        mast[j] = (float)Ub[(segb << 14) + (size_t)row*128 + cdv];
        memT[l15*136 + row] = (bf16)mast[j];
    }
    __syncthreads();

    float nrm[4][8];
    {
        const float* np = ksum + segb*128;
        #pragma unroll
        for (int ks = 0; ks < 4; ks++) {
            float4 a0 = *(const float4*)(np + ks*32 + lk);
            float4 a1 = *(const float4*)(np + ks*32 + lk + 4);
            nrm[ks][0]=a0.x; nrm[ks][1]=a0.y; nrm[ks][2]=a0.z; nrm[ks][3]=a0.w;
            nrm[ks][4]=a1.x; nrm[ks][5]=a1.y; nrm[ks][6]=a1.z; nrm[ks][7]=a1.w;
        }
    }

    bf16x8 qA[4], kA[4], qB[4], kB[4];

    auto loadraw = [&](int n2, bf16x8* qr, bf16x8* kr) {
        #pragma unroll
        for (int ks = 0; ks < 4; ks++) {
            const size_t base =
                ((size_t)(n2*SEGLEN + srow + l15)*NBATCH + b)*QKV_N
                + h*DHEAD + ks*32 + lk;
            qr[ks] = *(const bf16x8*)(qkv + base);
            kr[ks] = *(const bf16x8*)(qkv + base + DMODEL);
        }
    };

    auto step = [&](int n, bf16x8* curq, bf16x8* curk, bf16x8* nxtq, bf16x8* nxtk) {
        float uval[4], lv[4];
        #pragma unroll
        for (int j = 0; j < 4; j++) {
            const int sx = srow + r0 + j;
            uval[j] = (float)Ub[((segb + n) << 14) + (size_t)sx*128 + cdv];
            lv[j] = (float)lob[((size_t)(n*SEGLEN + sx)*NBATCH + b)*DMODEL
                               + h*DHEAD + cdv];
        }
        float dqv[4], ivk[4];
        {
            float aq = 0.f, ak = 0.f;
            #pragma unroll
            for (int ks = 0; ks < 4; ks++)
                #pragma unroll
                for (int e = 0; e < 8; e++) {
                    aq += (float)curq[ks][e] * nrm[ks][e];
                    ak += (float)curk[ks][e] * nrm[ks][e];
                }
            aq += __shfl_xor(aq, 16); aq += __shfl_xor(aq, 32);
            ak += __shfl_xor(ak, 16); ak += __shfl_xor(ak, 32);
            #pragma unroll
            for (int j = 0; j < 4; j++) {
                dqv[j] = __shfl(aq, r0 + j);
                ivk[j] = 1.f / __shfl(ak, r0 + j);
            }
        }
        {
            const float* np = ksum + (segb + n)*128;
            #pragma unroll
            for (int ks = 0; ks < 4; ks++) {
                float4 a0 = *(const float4*)(np + ks*32 + lk);
                float4 a1 = *(const float4*)(np + ks*32 + lk + 4);
                nrm[ks][0]+=a0.x; nrm[ks][1]+=a0.y; nrm[ks][2]+=a0.z; nrm[ks][3]+=a0.w;
                nrm[ks][4]+=a1.x; nrm[ks][5]+=a1.y; nrm[ks][6]+=a1.z; nrm[ks][7]+=a1.w;
            }
        }
        #pragma unroll
        for (int ks = 0; ks < 4; ks++)
            #pragma unroll
            for (int e = 0; e < 8; e++)
                skT[(ks*32 + lk + e)*136 + srow + l15] = curk[ks][e];
        f32x4 racc, yacc;
        #pragma unroll
        for (int e = 0; e < 4; e++) { racc[e] = 0.f; yacc[e] = 0.f; }
        #pragma unroll
        for (int ks = 0; ks < 4; ks++) {
            bf16x8 bm = *(const bf16x8*)&memT[l15*136 + ks*32 + lk];
            racc = mfma16x16x32(curq[ks], bm, racc);
            yacc = mfma16x16x32(curk[ks], bm, yacc);
        }
        if (n < NSEG - 1) loadraw(n + 1, nxtq, nxtk);
        #pragma unroll
        for (int j = 0; j < 4; j++)
            yT[l15*136 + srow + r0 + j] = (bf16)(yacc[j] * ivk[j]);
        __syncthreads();
        f32x4 zacc;
        #pragma unroll
        for (int e = 0; e < 4; e++) zacc[e] = 0.f;
        #pragma unroll
        for (int ks = 0; ks < 4; ks++) {
            bf16x8 bz = *(const bf16x8*)&yT[l15*136 + ks*32 + lk];
            bf16x8 az = *(const bf16x8*)&skT[(srow + l15)*136 + ks*32 + lk];
            zacc = mfma16x16x32(az, bz, zacc);
        }
        #pragma unroll
        for (int j = 0; j < 4; j++) {
            const int sx = srow + r0 + j;
            const float rv = racc[j] / dqv[j];
            lob[((size_t)(n*SEGLEN + sx)*NBATCH + b)*DMODEL + h*DHEAD + cdv] =
                (bf16)(lv[j] + g * rv);
            mast[j] += uval[j] - zacc[j];
            memT[l15*136 + sx] = (bf16)mast[j];
        }
        __syncthreads();
    };

    loadraw(1, qA, kA);
    for (int n = 1; n < NSEG; n += 2) {
        step(n, qA, kA, qB, kB);
        if (n + 1 < NSEG) step(n + 1, qB, kB, qA, kA);
    }
}

// ---------------------------------------------------------------------------
// Workspace layout (max 295,698,432 B, proven-safe):
//   [0)            qkvb  157,286,400
//   [157,286,400)  lob    52,428,800
//   [209,715,200)  woT     8,388,608
//   [218,103,808)  abf    52,428,800   -> reused as Ub (bf16) after QKV GEMM
//   [270,532,608)  wqkvT  25,165,824   -> reused as ksum
// ---------------------------------------------------------------------------
extern "C" void kernel_launch(void* const* d_in, const int* in_sizes, int n_in,
                              void* d_out, int out_size, void* d_ws, size_t ws_size,
                              hipStream_t stream)
{
    (void)in_sizes; (void)n_in; (void)out_size; (void)ws_size;
    const float* hidden = (const float*)d_in[0];
    const float* w_qkv  = (const float*)d_in[2];
    const float* w_o    = (const float*)d_in[3];
    const float* bal    = (const float*)d_in[4];

    char* ws = (char*)d_ws;
    bf16*  qkvb  = (bf16*)ws;
    bf16*  lob   = (bf16*)(ws + 157286400);
    bf16*  woT   = (bf16*)(ws + 209715200);
    bf16*  abf   = (bf16*)(ws + 218103808);
    bf16*  Ub    = abf;
    bf16*  wqkvT = (bf16*)(ws + 270532608);
    float* ksum  = (float*)(ws + 270532608);

    dim3 blk(256);
    prep_inputs<<<18432, blk, 0, stream>>>(hidden, abf, w_qkv, wqkvT, w_o, woT);

    gemm256<true><<<dim3(MROWS/256, QKV_N/256), 512, 0, stream>>>(abf, wqkvT, qkvb, QKV_N);

    attn_local<<<NSEG*NBATCH*NHEADS, 512, 0, stream>>>(qkvb, lob, bal, ksum, Ub);
    scan2<<<256, 512, 0, stream>>>(qkvb, Ub, ksum, lob, bal);

    gemm256<false><<<dim3(MROWS/256, DMODEL/256), 512, 0, stream>>>(lob, woT, d_out, DMODEL);
}

// Round 19
// 746.129 us; speedup vs baseline: 1.1826x; 1.0066x over previous
//
#include <hip/hip_runtime.h>
#include <hip/hip_bf16.h>

typedef __bf16 bf16;
typedef __bf16 bf16x8 __attribute__((ext_vector_type(8)));
typedef __bf16 bf16x4 __attribute__((ext_vector_type(4)));
typedef float  f32x4  __attribute__((ext_vector_type(4)));

#define S_LEN   6400
#define NBATCH  2
#define DMODEL  2048
#define NHEADS  16
#define DHEAD   128
#define NSEG    50
#define SEGLEN  128
#define MROWS   (S_LEN*NBATCH)     // 12800
#define QKV_N   (3*DMODEL)         // 6144

static __device__ __forceinline__ f32x4 mfma16x16x32(bf16x8 a, bf16x8 b, f32x4 c) {
    return __builtin_amdgcn_mfma_f32_16x16x32_bf16(a, b, c, 0, 0, 0);
}
static __device__ __forceinline__ void gload_lds16(const bf16* g, bf16* l) {
    __builtin_amdgcn_global_load_lds(
        (const __attribute__((address_space(1))) void*)g,
        (__attribute__((address_space(3))) void*)l, 16, 0, 0);
}
static __device__ __forceinline__ float elu1(float x) {
    return x > 0.f ? x + 1.f : __expf(x);
}

// ---------------------------------------------------------------------------
// prep_inputs: one launch for {fp32->bf16 hidden, W_qkv^T, W_o^T}.
// ---------------------------------------------------------------------------
__global__ void prep_inputs(const float* __restrict__ hidden, bf16* __restrict__ abf,
                            const float* __restrict__ w_qkv, bf16* __restrict__ wqkvT,
                            const float* __restrict__ w_o,   bf16* __restrict__ woT)
{
    __shared__ float tile[32][33];
    const int bid = blockIdx.x;
    if (bid < 2048) {
        const int n8 = MROWS*DMODEL/8;
        const int stride = 2048 * 256;
        for (int i = bid * 256 + threadIdx.x; i < n8; i += stride) {
            const float4* p = (const float4*)(hidden + (size_t)i * 8);
            float4 v0 = p[0], v1 = p[1];
            bf16x8 o;
            o[0]=(bf16)v0.x; o[1]=(bf16)v0.y; o[2]=(bf16)v0.z; o[3]=(bf16)v0.w;
            o[4]=(bf16)v1.x; o[5]=(bf16)v1.y; o[6]=(bf16)v1.z; o[7]=(bf16)v1.w;
            *(bf16x8*)(abf + (size_t)i * 8) = o;
        }
        return;
    }
    const float* W; bf16* WT; int N, n0, k0;
    if (bid < 14336) {
        const int b2 = bid - 2048;
        W = w_qkv; WT = wqkvT; N = QKV_N;
        n0 = (b2 % 192) * 32; k0 = (b2 / 192) * 32;
    } else {
        const int b3 = bid - 14336;
        W = w_o; WT = woT; N = DMODEL;
        n0 = (b3 % 64) * 32; k0 = (b3 / 64) * 32;
    }
    const int tx = threadIdx.x & 31, ty = threadIdx.x >> 5;
    #pragma unroll
    for (int i = 0; i < 4; i++) {
        int kk = ty + i * 8;
        tile[kk][tx] = W[(size_t)(k0 + kk) * N + n0 + tx];
    }
    __syncthreads();
    #pragma unroll
    for (int i = 0; i < 4; i++) {
        int nn = ty + i * 8;
        WT[(size_t)(n0 + nn) * DMODEL + k0 + tx] = (bf16)tile[tx][nn];
    }
}

// ---------------------------------------------------------------------------
// gemm256 (r9 champion, 2D grid — XCD swizzle REFUTED r14: operands L3-fit).
// 256x256 tile, BK=32, 512 thr, phase-split read-ahead, counted vmcnt(4),
// swizzled LDS (0 conflicts). 1001 TF, MfmaUtil 45.6%.
// ---------------------------------------------------------------------------
template<bool CBF16>
__global__ __launch_bounds__(512, 2) void gemm256(const bf16* __restrict__ A,
                                                  const bf16* __restrict__ BT,
                                                  void* __restrict__ Cptr, int Ndim)
{
    constexpr int K = DMODEL;
    constexpr int NT = K / 32;
    __shared__ __align__(16) bf16 a_sm[2][256*32];
    __shared__ __align__(16) bf16 b_sm[2][256*32];

    const int tid = threadIdx.x;
    const int l = tid & 63, wid = tid >> 6;
    const int wm = wid >> 2, wn = wid & 3;
    const int brow = blockIdx.x * 256, bcol = blockIdx.y * 256;
    const int l15 = l & 15, lg = l >> 4;

    const int st_mr  = tid >> 3;
    const int st_s0  = (tid & 7) ^ (st_mr & 7);
    const int st_row = 2 * st_mr + (st_s0 >> 2);
    const int st_col = (st_s0 & 3) << 3;
    const bf16* Asrc = A  + (size_t)(brow + st_row) * K + st_col;
    const bf16* Bsrc = BT + (size_t)(bcol + st_row) * K + st_col;

    int aoff[8], boff[4];
    #pragma unroll
    for (int mi = 0; mi < 8; mi++) {
        const int r = wm*128 + mi*16 + l15, mr = r >> 1;
        aoff[mi] = mr*64 + ((((( r & 1) << 2) | lg) ^ (mr & 7)) << 3);
    }
    #pragma unroll
    for (int ni = 0; ni < 4; ni++) {
        const int r = wn*64 + ni*16 + l15, mr = r >> 1;
        boff[ni] = mr*64 + ((((( r & 1) << 2) | lg) ^ (mr & 7)) << 3);
    }

    f32x4 acc[8][4];
    #pragma unroll
    for (int mi = 0; mi < 8; mi++)
        #pragma unroll
        for (int ni = 0; ni < 4; ni++)
            #pragma unroll
            for (int e = 0; e < 4; e++) acc[mi][ni][e] = 0.f;

    auto STAGE = [&](int buf, int kt2) {
        const int k0 = kt2 * 32;
        #pragma unroll
        for (int i = 0; i < 2; i++) {
            gload_lds16(Asrc + (size_t)(i*128) * K + k0, &a_sm[buf][i*4096 + tid*8]);
            gload_lds16(Bsrc + (size_t)(i*128) * K + k0, &b_sm[buf][i*4096 + tid*8]);
        }
    };

    bf16x8 af[4], ag[4], bfr[4];
    auto READ0 = [&](int buf) {
        #pragma unroll
        for (int mi = 0; mi < 4; mi++) af[mi]  = *(const bf16x8*)&a_sm[buf][aoff[mi]];
        #pragma unroll
        for (int ni = 0; ni < 4; ni++) bfr[ni] = *(const bf16x8*)&b_sm[buf][boff[ni]];
    };
    auto READ1 = [&](int buf) {
        #pragma unroll
        for (int mi = 0; mi < 4; mi++) ag[mi] = *(const bf16x8*)&a_sm[buf][aoff[4 + mi]];
    };
    auto MFMA_LO = [&]() {
        __builtin_amdgcn_s_setprio(1);
        #pragma unroll
        for (int mi = 0; mi < 4; mi++)
            #pragma unroll
            for (int ni = 0; ni < 4; ni++)
                acc[mi][ni] = mfma16x16x32(af[mi], bfr[ni], acc[mi][ni]);
        __builtin_amdgcn_s_setprio(0);
    };
    auto MFMA_HI = [&]() {
        __builtin_amdgcn_s_setprio(1);
        #pragma unroll
        for (int mi = 0; mi < 4; mi++)
            #pragma unroll
            for (int ni = 0; ni < 4; ni++)
                acc[4 + mi][ni] = mfma16x16x32(ag[mi], bfr[ni], acc[4 + mi][ni]);
        __builtin_amdgcn_s_setprio(0);
    };

    STAGE(0, 0);
    STAGE(1, 1);
    asm volatile("s_waitcnt vmcnt(4)" ::: "memory");
    __builtin_amdgcn_sched_barrier(0);
    __builtin_amdgcn_s_barrier();
    READ0(0);

    for (int tp = 0; tp < NT - 2; tp += 2) {
        READ1(0);
        __builtin_amdgcn_sched_barrier(0);
        MFMA_LO();
        asm volatile("s_waitcnt lgkmcnt(0)" ::: "memory");
        __builtin_amdgcn_sched_barrier(0);
        __builtin_amdgcn_s_barrier();
        STAGE(0, tp + 2);
        __builtin_amdgcn_sched_barrier(0);
        MFMA_HI();
        asm volatile("s_waitcnt vmcnt(4)" ::: "memory");
        __builtin_amdgcn_sched_barrier(0);
        __builtin_amdgcn_s_barrier();

        READ0(1);
        READ1(1);
        __builtin_amdgcn_sched_barrier(0);
        MFMA_LO();
        asm volatile("s_waitcnt lgkmcnt(0)" ::: "memory");
        __builtin_amdgcn_sched_barrier(0);
        __builtin_amdgcn_s_barrier();
        STAGE(1, tp + 3);
        __builtin_amdgcn_sched_barrier(0);
        MFMA_HI();
        asm volatile("s_waitcnt vmcnt(4)" ::: "memory");
        __builtin_amdgcn_sched_barrier(0);
        __builtin_amdgcn_s_barrier();
        READ0(0);
    }

    READ1(0);
    __builtin_amdgcn_sched_barrier(0);
    MFMA_LO();
    asm volatile("s_waitcnt lgkmcnt(0)" ::: "memory");
    __builtin_amdgcn_sched_barrier(0);
    MFMA_HI();
    asm volatile("s_waitcnt vmcnt(0)" ::: "memory");
    __builtin_amdgcn_sched_barrier(0);
    __builtin_amdgcn_s_barrier();
    READ0(1);
    READ1(1);
    __builtin_amdgcn_sched_barrier(0);
    MFMA_LO();
    asm volatile("s_waitcnt lgkmcnt(0)" ::: "memory");
    __builtin_amdgcn_sched_barrier(0);
    MFMA_HI();

    #pragma unroll
    for (int mi = 0; mi < 8; mi++)
        #pragma unroll
        for (int ni = 0; ni < 4; ni++) {
            const int row = brow + wm*128 + mi*16 + lg*4;
            const int col = bcol + wn*64 + ni*16 + l15;
            #pragma unroll
            for (int j = 0; j < 4; j++) {
                float v = acc[mi][ni][j];
                if (CBF16) ((bf16*)Cptr)[(size_t)(row + j) * Ndim + col] = (bf16)v;
                else       ((float*)Cptr)[(size_t)(row + j) * Ndim + col] = v;
            }
        }
}

// ---------------------------------------------------------------------------
// attn_local (r18 proven): 512 thr = 8 waves, wave owns 16 q-rows; 2
// waves/SIMD. lob=(1-g)*local; ksum; Ub=skT@v; in-place elu of q/k in qkvb.
// ---------------------------------------------------------------------------
__global__ __launch_bounds__(512, 1) void attn_local(bf16* __restrict__ qkv,
                                                     bf16* __restrict__ lob,
                                                     const float* __restrict__ bal,
                                                     float* __restrict__ ksum,
                                                     bf16* __restrict__ Ub)
{
    __shared__ bf16 qp_sm [128*136];
    __shared__ bf16 k_sm  [128*136];
    __shared__ bf16 vT_sm [128*136];
    __shared__ bf16 skT_sm[128*136];
    const int bid = blockIdx.x;
    const int h = bid & 15, b = (bid >> 4) & 1, n = bid >> 5;
    const int bh = b*NHEADS + h;
    const int tid = threadIdx.x, l = tid & 63, w = tid >> 6;   // w 0..7
    const int l15 = l & 15, lk = (l >> 4) * 8, r0 = (l >> 4) * 4;
    const float g  = 1.f / (1.f + __expf(-bal[h]));
    const float w1 = 1.f - g;

    {   // stage: 32 elems/thread (512 thr x 32 = 128x128)
        const int srow = tid >> 2, off = (tid & 3) << 5;
        const size_t gb = ((size_t)(n*SEGLEN + srow)*NBATCH + b)*QKV_N + h*DHEAD + off;
        bf16* qsrc = qkv + gb;
        bf16* ksrc = qkv + gb + DMODEL;
        const bf16* vsrc = qkv + gb + 2*DMODEL;
        #pragma unroll
        for (int j = 0; j < 32; j += 8) {
            bf16x8 qv = *(const bf16x8*)(qsrc + j);
            bf16x8 kv = *(const bf16x8*)(ksrc + j);
            bf16x8 vv = *(const bf16x8*)(vsrc + j);
            bf16x8 sqv, skv;
            #pragma unroll
            for (int e = 0; e < 8; e++) {
                sqv[e] = (bf16)elu1((float)qv[e]);
                skv[e] = (bf16)elu1((float)kv[e]);
            }
            *(bf16x8*)&qp_sm[srow*136 + off + j] = qv;
            *(bf16x8*)&k_sm [srow*136 + off + j] = kv;
            #pragma unroll
            for (int e = 0; e < 8; e++) {
                vT_sm [(off + j + e)*136 + srow] = vv[e];
                skT_sm[(off + j + e)*136 + srow] = skv[e];
            }
            *(bf16x8*)(qsrc + j) = sqv;   // in-place elu for scan2
            *(bf16x8*)(ksrc + j) = skv;
        }
    }
    __syncthreads();

    // ---- S = q @ k^T : wave w owns q-rows w*16..w*16+15
    f32x4 sc[8];
    #pragma unroll
    for (int ni = 0; ni < 8; ni++)
        #pragma unroll
        for (int e = 0; e < 4; e++) sc[ni][e] = 0.f;
    #pragma unroll
    for (int ks = 0; ks < 4; ks++) {
        const int ko = ks*32 + lk;
        bf16x8 aq = *(const bf16x8*)&qp_sm[(w*16 + l15)*136 + ko];
        bf16x8 bk[8];
        #pragma unroll
        for (int ni = 0; ni < 8; ni++)
            bk[ni] = *(const bf16x8*)&k_sm[(ni*16 + l15)*136 + ko];
        #pragma unroll
        for (int ni = 0; ni < 8; ni++)
            sc[ni] = mfma16x16x32(aq, bk[ni], sc[ni]);
    }
    __syncthreads();

    const float scale = 0.088388347648318433f;
    #pragma unroll
    for (int j = 0; j < 4; j++) {
        const int R = w*16 + r0 + j;
        float v[8]; float mx = -1e30f;
        #pragma unroll
        for (int ni = 0; ni < 8; ni++) {
            float x = sc[ni][j] * scale;
            if (ni*16 + l15 > R) x = -1e9f;
            v[ni] = x; mx = fmaxf(mx, x);
        }
        #pragma unroll
        for (int d = 1; d < 16; d <<= 1) mx = fmaxf(mx, __shfl_xor(mx, d));
        float sum = 0.f;
        #pragma unroll
        for (int ni = 0; ni < 8; ni++) { v[ni] = __expf(v[ni] - mx); sum += v[ni]; }
        #pragma unroll
        for (int d = 1; d < 16; d <<= 1) sum += __shfl_xor(sum, d);
        const float inv = 1.f / sum;
        #pragma unroll
        for (int ni = 0; ni < 8; ni++)
            qp_sm[R*136 + ni*16 + l15] = (bf16)(v[ni] * inv);
    }
    __syncthreads();

    // ---- O = P @ V
    f32x4 o[8];
    #pragma unroll
    for (int ni = 0; ni < 8; ni++)
        #pragma unroll
        for (int e = 0; e < 4; e++) o[ni][e] = 0.f;
    #pragma unroll
    for (int ks = 0; ks < 4; ks++) {
        const int ko = ks*32 + lk;
        bf16x8 ap = *(const bf16x8*)&qp_sm[(w*16 + l15)*136 + ko];
        bf16x8 bv[8];
        #pragma unroll
        for (int ni = 0; ni < 8; ni++)
            bv[ni] = *(const bf16x8*)&vT_sm[(ni*16 + l15)*136 + ko];
        #pragma unroll
        for (int ni = 0; ni < 8; ni++)
            o[ni] = mfma16x16x32(ap, bv[ni], o[ni]);
    }

    #pragma unroll
    for (int ni = 0; ni < 8; ni++) {
        const int R = w*16 + r0;
        const int c = ni*16 + l15;
        #pragma unroll
        for (int j = 0; j < 4; j++)
            lob[((size_t)(n*SEGLEN + R + j)*NBATCH + b)*DMODEL + h*DHEAD + c] =
                (bf16)(w1 * o[ni][j]);
    }

    if (tid < 128) {
        float a = 0.f;
        const bf16* row = &skT_sm[tid*136];
        #pragma unroll
        for (int ss = 0; ss < 128; ss += 8) {
            bf16x8 v8 = *(const bf16x8*)(row + ss);
            #pragma unroll
            for (int e = 0; e < 8; e++) a += (float)v8[e];
        }
        ksum[((size_t)bh*NSEG + n)*128 + tid] = a;
    }

    {
        const int wr = w >> 2, wc = w & 3;
        const size_t seg = (size_t)bh*NSEG + n;
        f32x4 ua[4][2];
        #pragma unroll
        for (int mi = 0; mi < 4; mi++)
            #pragma unroll
            for (int ni = 0; ni < 2; ni++)
                #pragma unroll
                for (int e = 0; e < 4; e++) ua[mi][ni][e] = 0.f;
        #pragma unroll
        for (int ks = 0; ks < 4; ks++) {
            const int ko = ks*32 + lk;
            bf16x8 auf[4], bv2[2];
            #pragma unroll
            for (int mi = 0; mi < 4; mi++)
                auf[mi] = *(const bf16x8*)&skT_sm[(wr*64 + mi*16 + l15)*136 + ko];
            #pragma unroll
            for (int ni = 0; ni < 2; ni++)
                bv2[ni] = *(const bf16x8*)&vT_sm[(wc*32 + ni*16 + l15)*136 + ko];
            #pragma unroll
            for (int mi = 0; mi < 4; mi++)
                #pragma unroll
                for (int ni = 0; ni < 2; ni++)
                    ua[mi][ni] = mfma16x16x32(auf[mi], bv2[ni], ua[mi][ni]);
        }
        #pragma unroll
        for (int mi = 0; mi < 4; mi++)
            #pragma unroll
            for (int ni = 0; ni < 2; ni++) {
                const int row = wr*64 + mi*16 + r0, col = wc*32 + ni*16 + l15;
                #pragma unroll
                for (int j = 0; j < 4; j++)
                    Ub[(seg << 14) + (size_t)(row + j)*128 + col] = (bf16)ua[mi][ni][j];
            }
    }
}

// ---------------------------------------------------------------------------
// scan2 (r19): loadraw(n+1) issued BEFORE the r/y MFMA cluster (r9 lesson:
// loads fly under MFMA + the z-phase instead of just the z-phase). Otherwise
// r17 structure: 512 thr = 8 waves, wave owns 16 rows, 2 waves/SIMD,
// pre-elu'd sq/sk, register norm prefix. Grid 256.
// ---------------------------------------------------------------------------
__global__ __launch_bounds__(512, 1) void scan2(const bf16* __restrict__ qkv,
                                                const bf16* __restrict__ Ub,
                                                const float* __restrict__ ksum,
                                                bf16* __restrict__ lob,
                                                const float* __restrict__ bal)
{
    __shared__ bf16 memT[16*136];
    __shared__ bf16 skT [128*136];
    __shared__ bf16 yT  [16*136];
    const int bid = blockIdx.x;
    const int bh = bid & 31, dq = bid >> 5;
    const int b = bh >> 4, h = bh & 15;
    const int tid = threadIdx.x, l = tid & 63, w = tid >> 6;   // w 0..7
    const int l15 = l & 15, lk = (l >> 4) * 8, r0 = (l >> 4) * 4;
    const int srow = w * 16;
    const float g = 1.f / (1.f + __expf(-bal[h]));
    const size_t segb = (size_t)bh * NSEG;
    const int cdv = dq*16 + l15;

    float mast[4];
    #pragma unroll
    for (int j = 0; j < 4; j++) {
        const int row = srow + r0 + j;
        mast[j] = (float)Ub[(segb << 14) + (size_t)row*128 + cdv];
        memT[l15*136 + row] = (bf16)mast[j];
    }
    __syncthreads();

    float nrm[4][8];
    {
        const float* np = ksum + segb*128;
        #pragma unroll
        for (int ks = 0; ks < 4; ks++) {
            float4 a0 = *(const float4*)(np + ks*32 + lk);
            float4 a1 = *(const float4*)(np + ks*32 + lk + 4);
            nrm[ks][0]=a0.x; nrm[ks][1]=a0.y; nrm[ks][2]=a0.z; nrm[ks][3]=a0.w;
            nrm[ks][4]=a1.x; nrm[ks][5]=a1.y; nrm[ks][6]=a1.z; nrm[ks][7]=a1.w;
        }
    }

    bf16x8 qA[4], kA[4], qB[4], kB[4];

    auto loadraw = [&](int n2, bf16x8* qr, bf16x8* kr) {
        #pragma unroll
        for (int ks = 0; ks < 4; ks++) {
            const size_t base =
                ((size_t)(n2*SEGLEN + srow + l15)*NBATCH + b)*QKV_N
                + h*DHEAD + ks*32 + lk;
            qr[ks] = *(const bf16x8*)(qkv + base);
            kr[ks] = *(const bf16x8*)(qkv + base + DMODEL);
        }
    };

    auto step = [&](int n, bf16x8* curq, bf16x8* curk, bf16x8* nxtq, bf16x8* nxtk) {
        float uval[4], lv[4];
        #pragma unroll
        for (int j = 0; j < 4; j++) {
            const int sx = srow + r0 + j;
            uval[j] = (float)Ub[((segb + n) << 14) + (size_t)sx*128 + cdv];
            lv[j] = (float)lob[((size_t)(n*SEGLEN + sx)*NBATCH + b)*DMODEL
                               + h*DHEAD + cdv];
        }
        float dqv[4], ivk[4];
        {
            float aq = 0.f, ak = 0.f;
            #pragma unroll
            for (int ks = 0; ks < 4; ks++)
                #pragma unroll
                for (int e = 0; e < 8; e++) {
                    aq += (float)curq[ks][e] * nrm[ks][e];
                    ak += (float)curk[ks][e] * nrm[ks][e];
                }
            aq += __shfl_xor(aq, 16); aq += __shfl_xor(aq, 32);
            ak += __shfl_xor(ak, 16); ak += __shfl_xor(ak, 32);
            #pragma unroll
            for (int j = 0; j < 4; j++) {
                dqv[j] = __shfl(aq, r0 + j);
                ivk[j] = 1.f / __shfl(ak, r0 + j);
            }
        }
        {
            const float* np = ksum + (segb + n)*128;
            #pragma unroll
            for (int ks = 0; ks < 4; ks++) {
                float4 a0 = *(const float4*)(np + ks*32 + lk);
                float4 a1 = *(const float4*)(np + ks*32 + lk + 4);
                nrm[ks][0]+=a0.x; nrm[ks][1]+=a0.y; nrm[ks][2]+=a0.z; nrm[ks][3]+=a0.w;
                nrm[ks][4]+=a1.x; nrm[ks][5]+=a1.y; nrm[ks][6]+=a1.z; nrm[ks][7]+=a1.w;
            }
        }
        #pragma unroll
        for (int ks = 0; ks < 4; ks++)
            #pragma unroll
            for (int e = 0; e < 8; e++)
                skT[(ks*32 + lk + e)*136 + srow + l15] = curk[ks][e];
        // issue next-step global loads BEFORE the MFMA cluster (fly under it)
        if (n < NSEG - 1) loadraw(n + 1, nxtq, nxtk);
        f32x4 racc, yacc;
        #pragma unroll
        for (int e = 0; e < 4; e++) { racc[e] = 0.f; yacc[e] = 0.f; }
        #pragma unroll
        for (int ks = 0; ks < 4; ks++) {
            bf16x8 bm = *(const bf16x8*)&memT[l15*136 + ks*32 + lk];
            racc = mfma16x16x32(curq[ks], bm, racc);
            yacc = mfma16x16x32(curk[ks], bm, yacc);
        }
        #pragma unroll
        for (int j = 0; j < 4; j++)
            yT[l15*136 + srow + r0 + j] = (bf16)(yacc[j] * ivk[j]);
        __syncthreads();
        f32x4 zacc;
        #pragma unroll
        for (int e = 0; e < 4; e++) zacc[e] = 0.f;
        #pragma unroll
        for (int ks = 0; ks < 4; ks++) {
            bf16x8 bz = *(const bf16x8*)&yT[l15*136 + ks*32 + lk];
            bf16x8 az = *(const bf16x8*)&skT[(srow + l15)*136 + ks*32 + lk];
            zacc = mfma16x16x32(az, bz, zacc);
        }
        #pragma unroll
        for (int j = 0; j < 4; j++) {
            const int sx = srow + r0 + j;
            const float rv = racc[j] / dqv[j];
            lob[((size_t)(n*SEGLEN + sx)*NBATCH + b)*DMODEL + h*DHEAD + cdv] =
                (bf16)(lv[j] + g * rv);
            mast[j] += uval[j] - zacc[j];
            memT[l15*136 + sx] = (bf16)mast[j];
        }
        __syncthreads();
    };

    loadraw(1, qA, kA);
    for (int n = 1; n < NSEG; n += 2) {
        step(n, qA, kA, qB, kB);
        if (n + 1 < NSEG) step(n + 1, qB, kB, qA, kA);
    }
}

// ---------------------------------------------------------------------------
// Workspace layout (max 295,698,432 B, proven-safe):
//   [0)            qkvb  157,286,400
//   [157,286,400)  lob    52,428,800
//   [209,715,200)  woT     8,388,608
//   [218,103,808)  abf    52,428,800   -> reused as Ub (bf16) after QKV GEMM
//   [270,532,608)  wqkvT  25,165,824   -> reused as ksum
// ---------------------------------------------------------------------------
extern "C" void kernel_launch(void* const* d_in, const int* in_sizes, int n_in,
                              void* d_out, int out_size, void* d_ws, size_t ws_size,
                              hipStream_t stream)
{
    (void)in_sizes; (void)n_in; (void)out_size; (void)ws_size;
    const float* hidden = (const float*)d_in[0];
    const float* w_qkv  = (const float*)d_in[2];
    const float* w_o    = (const float*)d_in[3];
    const float* bal    = (const float*)d_in[4];

    char* ws = (char*)d_ws;
    bf16*  qkvb  = (bf16*)ws;
    bf16*  lob   = (bf16*)(ws + 157286400);
    bf16*  woT   = (bf16*)(ws + 209715200);
    bf16*  abf   = (bf16*)(ws + 218103808);
    bf16*  Ub    = abf;
    bf16*  wqkvT = (bf16*)(ws + 270532608);
    float* ksum  = (float*)(ws + 270532608);

    dim3 blk(256);
    prep_inputs<<<18432, blk, 0, stream>>>(hidden, abf, w_qkv, wqkvT, w_o, woT);

    gemm256<true><<<dim3(MROWS/256, QKV_N/256), 512, 0, stream>>>(abf, wqkvT, qkvb, QKV_N);

    attn_local<<<NSEG*NBATCH*NHEADS, 512, 0, stream>>>(qkvb, lob, bal, ksum, Ub);
    scan2<<<256, 512, 0, stream>>>(qkvb, Ub, ksum, lob, bal);

    gemm256<false><<<dim3(MROWS/256, DMODEL/256), 512, 0, stream>>>(lob, woT, d_out, DMODEL);
}